// Round 8
// baseline (170.260 us; speedup 1.0000x reference)
//
#include <hip/hip_runtime.h>

#define B_   8
#define C_   128
#define N_   4096
#define C2_  64

typedef __bf16 bf16x8 __attribute__((ext_vector_type(8)));
typedef float  f32x4  __attribute__((ext_vector_type(4)));

#define MFMA16(a, b, c) __builtin_amdgcn_mfma_f32_16x16x32_bf16((a), (b), (c), 0, 0, 0)

// sqrt(log2(e)): fold into q/k so softmax uses exp2 directly (E' = E * log2e)
#define QK_SCALE 1.2011224087864498f

static __device__ __forceinline__ unsigned short f2bf(float f) {
    union { __bf16 b; unsigned short u; } cv;
    cv.b = (__bf16)f;
    return cv.u;
}
static __device__ __forceinline__ float bf2f(unsigned short u) {
    union { unsigned int u; float f; } cv;
    cv.u = ((unsigned int)u) << 16;
    return cv.f;
}

struct us4 { unsigned short a, b, c, d; };

// async global->LDS, 16 B per lane.  LDS dest must be linear in lane order.
static __device__ __forceinline__ void gl_lds16(const unsigned short* g, void* l) {
    __builtin_amdgcn_global_load_lds(
        (const __attribute__((address_space(1))) unsigned int*)g,
        (__attribute__((address_space(3))) unsigned int*)l,
        16, 0, 0);
}

// ---------------------------------------------------------------------------
// K1: fused projection GEMM.  D[192 o][64 n] = W(3x64 stacked)[o][c] * x[c][n]
//     per (b, 64-n tile).  Weights -> LDS bf16 [192][136]; x tile transposed
//     -> LDS bf16 x_t[64 n][136 c].  Epilogue: ot 0-3 -> qk_t (us4, *QK_SCALE);
//     ot 4-7 -> xv_bf (+b_v); ot 8-11 -> xc (f32).
// ---------------------------------------------------------------------------
__global__ __launch_bounds__(256) void k1_proj(
    const float* __restrict__ x, const float* __restrict__ w_qk,
    const float* __restrict__ w_v, const float* __restrict__ b_v,
    const float* __restrict__ w_x,
    unsigned short* __restrict__ qk_t, unsigned short* __restrict__ xv_bf,
    float* __restrict__ xc)
{
    __shared__ __align__(16) unsigned short w_lds[192 * 136];
    __shared__ __align__(16) unsigned short x_t[64 * 136];
    const int tid = threadIdx.x;
    const int wave = tid >> 6, lane = tid & 63;
    const int quad = lane >> 4, col = lane & 15;
    const int b = blockIdx.y;
    const int n0 = blockIdx.x * 64;

    const float* wsrc[3] = {w_qk, w_v, w_x};
    #pragma unroll
    for (int mat = 0; mat < 3; ++mat) {
        const float* wm = wsrc[mat];
        #pragma unroll
        for (int it = 0; it < 8; ++it) {
            const int idx = it * 256 + tid;            // [0, 2048)
            const int o = idx >> 5, c = (idx & 31) * 4;
            const float4 v = *(const float4*)(wm + o * C_ + c);
            us4 pk;
            pk.a = f2bf(v.x); pk.b = f2bf(v.y); pk.c = f2bf(v.z); pk.d = f2bf(v.w);
            *(us4*)&w_lds[(mat * 64 + o) * 136 + c] = pk;
        }
    }
    const float* xb = x + (size_t)b * C_ * N_ + n0;
    #pragma unroll
    for (int it = 0; it < 8; ++it) {
        const int idx = it * 256 + tid;                // [0, 2048)
        const int c = idx >> 4, n = (idx & 15) * 4;
        const float4 v = *(const float4*)(xb + (size_t)c * N_ + n);
        x_t[(n + 0) * 136 + c] = f2bf(v.x);
        x_t[(n + 1) * 136 + c] = f2bf(v.y);
        x_t[(n + 2) * 136 + c] = f2bf(v.z);
        x_t[(n + 3) * 136 + c] = f2bf(v.w);
    }
    __syncthreads();

    const int nw = wave * 16;
    bf16x8 bfr[4];
    #pragma unroll
    for (int kt = 0; kt < 4; ++kt)
        bfr[kt] = *(const bf16x8*)&x_t[(nw + col) * 136 + kt * 32 + quad * 8];

    const int n_g = n0 + nw + col;

    #pragma unroll
    for (int ot = 0; ot < 12; ++ot) {
        f32x4 acc = {0.f, 0.f, 0.f, 0.f};
        #pragma unroll
        for (int kt = 0; kt < 4; ++kt) {
            const bf16x8 afr = *(const bf16x8*)&w_lds[(ot * 16 + col) * 136 + kt * 32 + quad * 8];
            acc = MFMA16(afr, bfr[kt], acc);
        }
        if (ot < 4) {
            us4 pk;
            pk.a = f2bf(acc[0] * QK_SCALE); pk.b = f2bf(acc[1] * QK_SCALE);
            pk.c = f2bf(acc[2] * QK_SCALE); pk.d = f2bf(acc[3] * QK_SCALE);
            *(us4*)&qk_t[(size_t)(b * N_ + n_g) * C2_ + ot * 16 + quad * 4] = pk;
        } else if (ot < 8) {
            const float4 bv4 = *(const float4*)(b_v + (ot - 4) * 16 + quad * 4);
            const float* bvp = (const float*)&bv4;
            #pragma unroll
            for (int r = 0; r < 4; ++r)
                xv_bf[(size_t)(b * C2_ + (ot - 4) * 16 + quad * 4 + r) * N_ + n_g]
                    = f2bf(acc[r] + bvp[r]);
        } else {
            #pragma unroll
            for (int r = 0; r < 4; ++r)
                xc[(size_t)(b * C2_ + (ot - 8) * 16 + quad * 4 + r) * N_ + n_g] = acc[r];
        }
    }
}

// ---------------------------------------------------------------------------
// K2: partial row softmax sums.  Grid 2048: b=id&7, nblk=(id>>3)&31, mq=id>>8.
//     Wave owns 32 n-rows (2 A-frag sets); block owns 128 rows x 512 m as
//     4 chunks of 128 m (2x16 KB dbuf).  part_rs[mq][b][n].
// ---------------------------------------------------------------------------
__global__ __launch_bounds__(256) void k2_rowstats(
    const unsigned short* __restrict__ qk_t, float* __restrict__ part_rs)
{
    __shared__ __align__(16) unsigned char lds_raw[2 * 16384];
    const int tid = threadIdx.x;
    const int wave = tid >> 6, lane = tid & 63;
    const int quad = lane >> 4, col = lane & 15;
    const int b = blockIdx.x & 7;
    const int nblk = (blockIdx.x >> 3) & 31;
    const int mq = blockIdx.x >> 8;                   // 0..7
    const int n_base = nblk * 128 + wave * 32;
    const int m_start = mq * 512;
    const unsigned short* qb = qk_t + (size_t)b * N_ * C2_;

    // two persistent A-frag sets: rows n_base + s*16 + col
    bf16x8 a0[2], a1[2];
    #pragma unroll
    for (int s = 0; s < 2; ++s) {
        const unsigned short* p = qb + (size_t)(n_base + s * 16 + col) * C2_ + quad * 8;
        a0[s] = *(const bf16x8*)p;
        a1[s] = *(const bf16x8*)(p + 32);
    }

    // stage 128 m-rows (16 KB) into buffer p
    auto stage = [&](int m0, int p) {
        unsigned char* base = lds_raw + p * 16384;
        #pragma unroll
        for (int r = 0; r < 4; ++r) {
            const int idx = r * 256 + tid;             // [0, 1024)
            const int row = idx >> 3, seg = idx & 7;
            gl_lds16(qb + (size_t)(m0 + row) * C2_ + (size_t)(seg ^ (row & 7)) * 8,
                     base + idx * 16);
        }
    };

    float run_s[2][4];
    #pragma unroll
    for (int s = 0; s < 2; ++s)
        #pragma unroll
        for (int r = 0; r < 4; ++r) run_s[s][r] = 0.f;

    stage(m_start, 0);

    for (int c = 0; c < 4; ++c) {
        const int p = c & 1;
        asm volatile("s_waitcnt vmcnt(0)" ::: "memory");   // prev stage landed (issued 1 chunk ago)
        __builtin_amdgcn_s_barrier();
        asm volatile("" ::: "memory");
        if (c + 1 < 4) stage(m_start + (c + 1) * 128, 1 - p);
        const unsigned short* qt = (const unsigned short*)(lds_raw + p * 16384);
        #pragma unroll
        for (int ms = 0; ms < 8; ++ms) {
            const int row = ms * 16 + col;
            const bf16x8 b0 = *(const bf16x8*)(qt + row * 64 + ((quad ^ (col & 7)) * 8));
            const bf16x8 b1 = *(const bf16x8*)(qt + row * 64 + (((4 + quad) ^ (col & 7)) * 8));
            #pragma unroll
            for (int s = 0; s < 2; ++s) {
                f32x4 acc = {0.f, 0.f, 0.f, 0.f};
                __builtin_amdgcn_s_setprio(1);
                acc = MFMA16(a0[s], b0, acc);
                acc = MFMA16(a1[s], b1, acc);
                __builtin_amdgcn_s_setprio(0);
                #pragma unroll
                for (int r = 0; r < 4; ++r)
                    run_s[s][r] += __builtin_amdgcn_exp2f(acc[r]);
            }
        }
    }

    #pragma unroll
    for (int s = 0; s < 2; ++s)
        #pragma unroll
        for (int r = 0; r < 4; ++r) {
            #pragma unroll
            for (int off = 1; off < 16; off <<= 1)
                run_s[s][r] += __shfl_xor(run_s[s][r], off, 64);
        }
    if (col == 0) {
        #pragma unroll
        for (int s = 0; s < 2; ++s)
            #pragma unroll
            for (int r = 0; r < 4; ++r)
                part_rs[((size_t)(mq * 8 + b) << 12) + n_base + s * 16 + quad * 4 + r]
                    = run_s[s][r];
    }
}

// ---------------------------------------------------------------------------
// K2bc: fused rowsum-combine + xv scale.  Grid 512: b=id&7, nt=id>>3.
//       winv = 1/rowsum (LDS-local); wbf = bf16(winv); xv *= winv in place.
// ---------------------------------------------------------------------------
__global__ __launch_bounds__(256) void k2bc(
    const float* __restrict__ part_rs, unsigned short* __restrict__ xv_bf,
    unsigned short* __restrict__ wbf)
{
    __shared__ float wl[64];
    const int tid = threadIdx.x;
    const int b = blockIdx.x & 7;
    const int n0 = (blockIdx.x >> 3) * 64;
    if (tid < 64) {
        float s = 0.f;
        #pragma unroll
        for (int q = 0; q < 8; ++q)
            s += part_rs[((size_t)(q * 8 + b) << 12) + n0 + tid];
        const float w = 1.0f / s;
        wl[tid] = w;
        wbf[b * N_ + n0 + tid] = f2bf(w);
    }
    __syncthreads();
    #pragma unroll
    for (int it = 0; it < 4; ++it) {
        const int idx4 = it * 256 + tid;               // [0, 1024)
        const int o = idx4 >> 4, n4 = (idx4 & 15) * 4;
        unsigned short* p = xv_bf + (size_t)(b * C2_ + o) * N_ + n0 + n4;
        us4 v = *(us4*)p;
        v.a = f2bf(bf2f(v.a) * wl[n4 + 0]);
        v.b = f2bf(bf2f(v.b) * wl[n4 + 1]);
        v.c = f2bf(bf2f(v.c) * wl[n4 + 2]);
        v.d = f2bf(bf2f(v.d) * wl[n4 + 3]);
        *(us4*)p = v;
    }
}

// ---------------------------------------------------------------------------
// K3: R7 structure + DEFERRED-PV software pipeline (T15: compute[c] || finish[c-1]).
//     R0 (3 w/SIMD) and R7 (4 w/SIMD) both sat at ~48us / 31% MfmaUtil: the
//     limiter is the per-chunk serial chain qa.ds_read -> E-MFMA -> exp2 ->
//     stS.ds_write -> lgkm -> sB.ds_read -> PV-MFMA -> barrier, not occupancy.
//     Fix: double-buffer the wave-private stS and run PV(c-1) during
//     iteration c: the stS write->read round-trip gets a full iteration of
//     separation, and PV's MFMAs overlay E's exp2/pack chain.  va/wfrag for
//     chunk c are lifted to registers in iteration c (vt[p] still valid) so
//     the deferred PV is pure reg+stS.  Barrier/DMA schedule unchanged
//     (1 __syncthreads per chunk).  LDS 73728 -> 2 blocks/CU.
//     launch_bounds(512,3): cap 170 >> natural ~140 -> spill impossible.
// ---------------------------------------------------------------------------
__global__ __launch_bounds__(512, 3) void k3_pv(
    const unsigned short* __restrict__ qk_t, const unsigned short* __restrict__ xv_bf,
    const unsigned short* __restrict__ wbf,
    unsigned short* __restrict__ yb0, unsigned short* __restrict__ yb1,
    float* __restrict__ cspart)
{
    // 0..16K: qk dbuf | 16K..32K: xv dbuf | 32K..72K: stS (8 waves x 2 bufs x 2560 B)
    __shared__ __align__(16) unsigned char lds_raw[32768 + 8 * 5120];
    const int tid = threadIdx.x;
    const int wave = tid >> 6, lane = tid & 63;
    const int quad = lane >> 4, col = lane & 15;
    const int nh2 = wave & 1, mh = wave >> 1;        // mh 0..3
    const int b = blockIdx.x & 7;
    const int m_blk = ((blockIdx.x >> 3) & 31) * 128;
    const int sk = blockIdx.x >> 8;                  // 0..1 (split-K index)
    const int n_start = sk * 2048;
    const int n_chunks = 32;
    const int m_wave = m_blk + mh * 32;
    const unsigned short* qb = qk_t + (size_t)b * N_ * C2_;
    const unsigned short* vb = xv_bf + (size_t)b * C2_ * N_;
    const unsigned short* wb = wbf + b * N_;
    unsigned short* yp = (sk == 0) ? yb0 : yb1;

    // persistent B-operands for E: this wave's 32 m-cols (2 groups of 16)
    bf16x8 kb0[2], kb1[2];
    #pragma unroll
    for (int g = 0; g < 2; ++g) {
        const unsigned short* p = qb + (size_t)(m_wave + g * 16 + col) * C2_ + quad * 8;
        kb0[g] = *(const bf16x8*)p;
        kb1[g] = *(const bf16x8*)(p + 32);
    }

    // wave-private stS, double-buffered: [buf][g][col][40] (1280 shorts per buf)
    unsigned short* stSb = (unsigned short*)(lds_raw + 32768 + wave * 5120);

    // stage one 64n qk slab + 64ch xv tile (8 KB each): 1 DMA/lane/array
    auto stage = [&](int n0, int p) {
        unsigned char* qbase = lds_raw + p * 8192;
        unsigned char* vbase = lds_raw + 16384 + p * 8192;
        const int row = tid >> 3, seg = tid & 7;
        const int ss = seg ^ (row & 7);
        gl_lds16(qb + (size_t)(n0 + row) * C2_ + (size_t)ss * 8, qbase + tid * 16);
        gl_lds16(vb + (size_t)row * N_ + n0 + ss * 8, vbase + tid * 16);
    };

    // E phase for chunk parity p: qt[p] -> stS[p]
    auto ephase = [&](int p) {
        const unsigned short* qt = (const unsigned short*)(lds_raw + p * 8192);
        unsigned short* stW = stSb + p * 1280;
        #pragma unroll
        for (int ns = 0; ns < 2; ++ns) {
            const int row = nh2 * 32 + ns * 16 + col;
            const bf16x8 qa0 = *(const bf16x8*)(qt + row * 64 + ((quad ^ (col & 7)) * 8));
            const bf16x8 qa1 = *(const bf16x8*)(qt + row * 64 + (((4 + quad) ^ (col & 7)) * 8));
            #pragma unroll
            for (int g = 0; g < 2; ++g) {
                f32x4 acc = {0.f, 0.f, 0.f, 0.f};
                acc = MFMA16(qa0, kb0[g], acc);
                acc = MFMA16(qa1, kb1[g], acc);
                union { unsigned short us[4]; uint2 u2; } pk;
                #pragma unroll
                for (int r = 0; r < 4; ++r)
                    pk.us[r] = f2bf(__builtin_amdgcn_exp2f(acc[r]));
                *(uint2*)&stW[(g * 16 + col) * 40 + ns * 16 + quad * 4] = pk.u2;
            }
        }
    };

    f32x4 accY[2][4];   // [g][os]
    #pragma unroll
    for (int g = 0; g < 2; ++g)
        #pragma unroll
        for (int os = 0; os < 4; ++os) accY[g][os] = (f32x4){0.f, 0.f, 0.f, 0.f};
    f32x4 csacc[2];
    #pragma unroll
    for (int g = 0; g < 2; ++g) csacc[g] = (f32x4){0.f, 0.f, 0.f, 0.f};

    const int vsw = ((nh2 * 4 + quad) ^ (col & 7)) * 8;  // xv LDS slot swizzle

    stage(n_start, 0);
    __syncthreads();                                  // chunk 0 staged
    stage(n_start + 64, 1);                           // chunk 1 in flight

    // E(0) + operand lift for PV(0)
    ephase(0);
    bf16x8 vaP[4], wfP;
    {
        const unsigned short* vt = (const unsigned short*)(lds_raw + 16384);
        #pragma unroll
        for (int os = 0; os < 4; ++os)
            vaP[os] = *(const bf16x8*)(vt + (os * 16 + col) * 64 + vsw);
        wfP = *(const bf16x8*)(wb + n_start + nh2 * 32 + quad * 8);
    }

    for (int c = 1; c < n_chunks; ++c) {
        const int n0 = n_start + c * 64;
        const int p = c & 1;
        __syncthreads();                              // chunk c staged; bufs[1-p] free
        if (c + 1 < n_chunks) stage(n0 + 64, 1 - p);

        // E(c): qt[p] -> stS[p]
        ephase(p);

        // lift chunk-c PV operands to registers (vt[p] valid until next barrier)
        bf16x8 vaC[4], wfC;
        {
            const unsigned short* vt = (const unsigned short*)(lds_raw + 16384 + p * 8192);
            #pragma unroll
            for (int os = 0; os < 4; ++os)
                vaC[os] = *(const bf16x8*)(vt + (os * 16 + col) * 64 + vsw);
            wfC = *(const bf16x8*)(wb + n0 + nh2 * 32 + quad * 8);
        }

        // deferred PV(c-1): sB from stS[1-p] (written last iteration -> no stall)
        {
            const unsigned short* stR = stSb + (1 - p) * 1280;
            bf16x8 sB[2];
            #pragma unroll
            for (int g = 0; g < 2; ++g)
                sB[g] = *(const bf16x8*)&stR[(g * 16 + col) * 40 + quad * 8];
            #pragma unroll
            for (int g = 0; g < 2; ++g)
                csacc[g] = MFMA16(wfP, sB[g], csacc[g]);
            #pragma unroll
            for (int os = 0; os < 4; ++os)
                #pragma unroll
                for (int g = 0; g < 2; ++g)
                    accY[g][os] = MFMA16(vaP[os], sB[g], accY[g][os]);
        }
        #pragma unroll
        for (int os = 0; os < 4; ++os) vaP[os] = vaC[os];
        wfP = wfC;
    }

    // final PV(n_chunks-1): stS[(n_chunks-1)&1] = stS[1]
    {
        const unsigned short* stR = stSb + 1280;
        bf16x8 sB[2];
        #pragma unroll
        for (int g = 0; g < 2; ++g)
            sB[g] = *(const bf16x8*)&stR[(g * 16 + col) * 40 + quad * 8];
        #pragma unroll
        for (int g = 0; g < 2; ++g)
            csacc[g] = MFMA16(wfP, sB[g], csacc[g]);
        #pragma unroll
        for (int os = 0; os < 4; ++os)
            #pragma unroll
            for (int g = 0; g < 2; ++g)
                accY[g][os] = MFMA16(vaP[os], sB[g], accY[g][os]);
    }

    // epilogue: combine the two n-halves (waves nh2=1 -> LDS; nh2=0 adds+writes)
    __syncthreads();
    float* cmb = (float*)lds_raw;              // 32 KB: [mh][g*4+os][r][lane]
    float* csc = (float*)(lds_raw + 32768);    // 2 KB:  [mh][g][lane]
    if (nh2 == 1) {
        #pragma unroll
        for (int g = 0; g < 2; ++g) {
            #pragma unroll
            for (int os = 0; os < 4; ++os)
                #pragma unroll
                for (int r = 0; r < 4; ++r)
                    cmb[((mh * 8 + g * 4 + os) * 4 + r) * 64 + lane] = accY[g][os][r];
            csc[(mh * 2 + g) * 64 + lane] = csacc[g][0];
        }
    }
    __syncthreads();
    if (nh2 == 0) {
        #pragma unroll
        for (int g = 0; g < 2; ++g) {
            const float cs = csacc[g][0] + csc[(mh * 2 + g) * 64 + lane];
            if (lane < 16)
                cspart[((size_t)sk * 8 + b) * N_ + m_wave + g * 16 + lane] = cs;
            #pragma unroll
            for (int os = 0; os < 4; ++os)
                #pragma unroll
                for (int r = 0; r < 4; ++r) {
                    const float v = accY[g][os][r] +
                        cmb[((mh * 8 + g * 4 + os) * 4 + r) * 64 + lane];
                    yp[(size_t)(b * C2_ + os * 16 + quad * 4 + r) * N_ + m_wave + g * 16 + col]
                        = f2bf(v);
                }
        }
    }
}

// ---------------------------------------------------------------------------
// K4: fused partial-combine + w_t GEMM (MFMA) + BN partial stats.
//     Grid (64, 8), 64-n tiles.  cinv = 1/(eps+sum cspart over 2 splits);
//     d = xc - (y0+y1)*cinv (y partials BF16 -> 8 MB read) staged TRANSPOSED
//     to LDS bf16 d_t[n][72]; w_t staged bf16 [o][72].  Wave = o-tile; K=64.
//     t = acc + b_t -> t_buf; per-block channel partials -> part_bn[c][blk].
// ---------------------------------------------------------------------------
__global__ __launch_bounds__(256) void k4_t(
    const float* __restrict__ xc, const unsigned short* __restrict__ y0,
    const unsigned short* __restrict__ y1,
    const float* __restrict__ cspart, const float* __restrict__ w_t,
    const float* __restrict__ b_t, float* __restrict__ t_buf,
    float* __restrict__ part_bn)
{
    __shared__ __align__(16) unsigned short wlds[64 * 72];
    __shared__ __align__(16) unsigned short d_t[64 * 72];
    __shared__ float cinv[64];
    const int tid = threadIdx.x;
    const int wave = tid >> 6, lane = tid & 63;
    const int quad = lane >> 4, col = lane & 15;
    const int b = blockIdx.y;
    const int n0 = blockIdx.x * 64;
    const size_t base = (size_t)b * C2_ * N_;

    // phase 0: w_t -> bf16 LDS; per-n colsum inverse
    #pragma unroll
    for (int it = 0; it < 4; ++it) {
        const int idx4 = it * 256 + tid;               // [0, 1024)
        const int o = idx4 >> 4, i4 = (idx4 & 15) * 4;
        const float4 v = *(const float4*)(w_t + o * 64 + i4);
        us4 pk;
        pk.a = f2bf(v.x); pk.b = f2bf(v.y); pk.c = f2bf(v.z); pk.d = f2bf(v.w);
        *(us4*)&wlds[o * 72 + i4] = pk;
    }
    if (tid < 64) {
        const int n = n0 + tid;
        const float cs = cspart[(size_t)b * N_ + n] + cspart[(size_t)(8 + b) * N_ + n];
        cinv[tid] = 1.0f / (1e-9f + cs);
    }
    __syncthreads();

    // phase 1: d = xc - (y0+y1)*cinv, transposed bf16 -> d_t[n][i]
    #pragma unroll
    for (int it = 0; it < 4; ++it) {
        const int idx4 = it * 256 + tid;               // [0, 1024)
        const int i = idx4 >> 4, n4 = (idx4 & 15) * 4;
        const size_t g = base + (size_t)i * N_ + n0 + n4;
        const float4 c4 = *(const float4*)(xc + g);
        const us4 u0 = *(const us4*)(y0 + g);
        const us4 u1 = *(const us4*)(y1 + g);
        d_t[(n4 + 0) * 72 + i] = f2bf(c4.x - (bf2f(u0.a) + bf2f(u1.a)) * cinv[n4 + 0]);
        d_t[(n4 + 1) * 72 + i] = f2bf(c4.y - (bf2f(u0.b) + bf2f(u1.b)) * cinv[n4 + 1]);
        d_t[(n4 + 2) * 72 + i] = f2bf(c4.z - (bf2f(u0.c) + bf2f(u1.c)) * cinv[n4 + 2]);
        d_t[(n4 + 3) * 72 + i] = f2bf(c4.w - (bf2f(u0.d) + bf2f(u1.d)) * cinv[n4 + 3]);
    }
    __syncthreads();

    const int ow = wave * 16;
    bf16x8 afr[2];
    #pragma unroll
    for (int kt = 0; kt < 2; ++kt)
        afr[kt] = *(const bf16x8*)&wlds[(ow + col) * 72 + kt * 32 + quad * 8];
    const float4 bt4 = *(const float4*)(b_t + ow + quad * 4);
    const float* btp = (const float*)&bt4;

    float s[4] = {0.f, 0.f, 0.f, 0.f}, q2[4] = {0.f, 0.f, 0.f, 0.f};
    #pragma unroll
    for (int ns = 0; ns < 4; ++ns) {
        f32x4 acc = {0.f, 0.f, 0.f, 0.f};
        #pragma unroll
        for (int kt = 0; kt < 2; ++kt) {
            const bf16x8 bfr = *(const bf16x8*)&d_t[(ns * 16 + col) * 72 + kt * 32 + quad * 8];
            acc = MFMA16(afr[kt], bfr, acc);
        }
        #pragma unroll
        for (int r = 0; r < 4; ++r) {
            const float t = acc[r] + btp[r];
            t_buf[base + (size_t)(ow + quad * 4 + r) * N_ + n0 + ns * 16 + col] = t;
            s[r] += t;
            q2[r] += t * t;
        }
    }
    #pragma unroll
    for (int r = 0; r < 4; ++r) {
        #pragma unroll
        for (int off = 1; off < 16; off <<= 1) {
            s[r]  += __shfl_xor(s[r],  off, 64);
            q2[r] += __shfl_xor(q2[r], off, 64);
        }
    }
    if (col == 0) {
        const int blk = blockIdx.x * 8 + b;            // [0, 512)
        #pragma unroll
        for (int r = 0; r < 4; ++r) {
            part_bn[(size_t)(ow + quad * 4 + r) * 512 + blk]      = s[r];
            part_bn[(size_t)(64 + ow + quad * 4 + r) * 512 + blk] = q2[r];
        }
    }
}

// K5r: bn[c] = sum_blk part_bn[c][blk], c in [0,128)
__global__ __launch_bounds__(256) void k5r(
    const float* __restrict__ part_bn, float* __restrict__ bn)
{
    const int c = blockIdx.x;
    const int tid = threadIdx.x, wave = tid >> 6, lane = tid & 63;
    float s = 0.f;
    for (int j = tid; j < 512; j += 256) s += part_bn[(size_t)c * 512 + j];
    #pragma unroll
    for (int off = 1; off < 64; off <<= 1) s += __shfl_xor(s, off, 64);
    __shared__ float red[4];
    if (lane == 0) red[wave] = s;
    __syncthreads();
    if (tid == 0) bn[c] = red[0] + red[1] + red[2] + red[3];
}

// ---------------------------------------------------------------------------
// K6: out = xc + relu(gamma * (t - mean) * rsqrt(var + eps) + beta)
// ---------------------------------------------------------------------------
__global__ __launch_bounds__(256) void k6_out(
    const float* __restrict__ xc, const float* __restrict__ t_buf,
    const float* __restrict__ bn, const float* __restrict__ gamma,
    const float* __restrict__ beta, float* __restrict__ out)
{
    const int idx = blockIdx.x * 256 + threadIdx.x;
    const int o = (idx >> 10) & 63;
    const float invC = 1.0f / (float)(B_ * N_);
    const float mean = bn[o] * invC;
    const float var  = bn[64 + o] * invC - mean * mean;
    const float sc = gamma[o] * rsqrtf(var + 1e-5f);
    const float sh = beta[o] - mean * sc;
    const float4 t4 = ((const float4*)t_buf)[idx];
    const float4 c4 = ((const float4*)xc)[idx];
    float4 r;
    r.x = c4.x + fmaxf(0.f, sc * t4.x + sh);
    r.y = c4.y + fmaxf(0.f, sc * t4.y + sh);
    r.z = c4.z + fmaxf(0.f, sc * t4.z + sh);
    r.w = c4.w + fmaxf(0.f, sc * t4.w + sh);
    ((float4*)out)[idx] = r;
}

extern "C" void kernel_launch(void* const* d_in, const int* in_sizes, int n_in,
                              void* d_out, int out_size, void* d_ws, size_t ws_size,
                              hipStream_t stream) {
    const float* x     = (const float*)d_in[0];
    const float* w_qk  = (const float*)d_in[1];
    const float* w_v   = (const float*)d_in[2];
    const float* b_v   = (const float*)d_in[3];
    const float* w_x   = (const float*)d_in[4];
    const float* w_t   = (const float*)d_in[5];
    const float* b_t   = (const float*)d_in[6];
    const float* gamma = (const float*)d_in[7];
    const float* beta  = (const float*)d_in[8];
    float* out = (float*)d_out;

    char* ws = (char*)d_ws;
    unsigned short* qk_t  = (unsigned short*)ws;                      // 4 MB
    unsigned short* xv_bf = (unsigned short*)(ws + (4  << 20));       // 4 MB
    float* xc      = (float*)(ws + (8  << 20));                       // 8 MB
    unsigned short* yb0 = (unsigned short*)(ws + (16 << 20));         // 4 MB (bf16 partial Y)
    unsigned short* yb1 = (unsigned short*)(ws + (20 << 20));         // 4 MB (bf16 partial Y)
    float* t_buf   = (float*)(ws + (24 << 20));                       // 8 MB
    float* part_rs = (float*)(ws + (32 << 20));                       // 1 MB (k2 -> k2bc)
    float* cspart  = (float*)(ws + (32 << 20));                       // 256 KB (k3 -> k4; reuses part_rs)
    unsigned short* wbf = (unsigned short*)(ws + (33 << 20));         // 64 KB
    float* part_bn = (float*)(ws + (33 << 20) + (64 << 10));          // 256 KB
    float* bn      = (float*)(ws + (33 << 20) + (320 << 10));         // 512 B

    hipLaunchKernelGGL(k1_proj,     dim3(64, 8),  256, 0, stream,
                       x, w_qk, w_v, b_v, w_x, qk_t, xv_bf, xc);
    hipLaunchKernelGGL(k2_rowstats, dim3(2048),   256, 0, stream, qk_t, part_rs);
    hipLaunchKernelGGL(k2bc,        dim3(512),    256, 0, stream, part_rs, xv_bf, wbf);
    hipLaunchKernelGGL(k3_pv,       dim3(512),    512, 0, stream,
                       qk_t, xv_bf, wbf, yb0, yb1, cspart);
    hipLaunchKernelGGL(k4_t,        dim3(64, 8),  256, 0, stream,
                       xc, yb0, yb1, cspart, w_t, b_t, t_buf, part_bn);
    hipLaunchKernelGGL(k5r,         dim3(128),    256, 0, stream, part_bn, bn);
    hipLaunchKernelGGL(k6_out,      dim3(2048),   256, 0, stream, xc, t_buf, bn, gamma, beta, out);
}

// Round 10
// 168.567 us; speedup vs baseline: 1.0100x; 1.0100x over previous
//
#include <hip/hip_runtime.h>

#define B_   8
#define C_   128
#define N_   4096
#define C2_  64

typedef __bf16 bf16x8 __attribute__((ext_vector_type(8)));
typedef float  f32x4  __attribute__((ext_vector_type(4)));

#define MFMA16(a, b, c) __builtin_amdgcn_mfma_f32_16x16x32_bf16((a), (b), (c), 0, 0, 0)

// sqrt(log2(e)): folded into w_qk by k0 so softmax uses exp2 directly
#define QK_SCALE 1.2011224087864498f

static __device__ __forceinline__ unsigned short f2bf(float f) {
    union { __bf16 b; unsigned short u; } cv;
    cv.b = (__bf16)f;
    return cv.u;
}
static __device__ __forceinline__ float bf2f(unsigned short u) {
    union { unsigned int u; float f; } cv;
    cv.u = ((unsigned int)u) << 16;
    return cv.f;
}

struct us4 { unsigned short a, b, c, d; };

// async global->LDS, 16 B per lane.  LDS dest must be linear in lane order.
static __device__ __forceinline__ void gl_lds16(const unsigned short* g, void* l) {
    __builtin_amdgcn_global_load_lds(
        (const __attribute__((address_space(1))) unsigned int*)g,
        (__attribute__((address_space(3))) unsigned int*)l,
        16, 0, 0);
}

// ---------------------------------------------------------------------------
// K0: one-time weight convert f32 -> bf16, stacked [w_qk; w_v; w_x] = [192][128].
//     QK_SCALE folded into w_qk rows (linear in the GEMM -> identical math to
//     scaling the qk output).  24576 elems, grid 24 x 256 x 4.
// ---------------------------------------------------------------------------
__global__ __launch_bounds__(256) void k0_wcvt(
    const float* __restrict__ wq, const float* __restrict__ wv,
    const float* __restrict__ wx, unsigned short* __restrict__ wst)
{
    const int i4 = (blockIdx.x * 256 + threadIdx.x) * 4;   // [0, 24576)
    const int mat = i4 >> 13;                              // 8192 elems / matrix
    const float* src = (mat == 0) ? wq : (mat == 1) ? wv : wx;
    const float sc = (mat == 0) ? QK_SCALE : 1.0f;
    const float4 v = *(const float4*)(src + (i4 & 8191));
    us4 pk;
    pk.a = f2bf(v.x * sc); pk.b = f2bf(v.y * sc);
    pk.c = f2bf(v.z * sc); pk.d = f2bf(v.w * sc);
    *(us4*)(wst + i4) = pk;
}

// ---------------------------------------------------------------------------
// K1: fused projection GEMM.  D[192 o][64 n] = Wst[o][c] * x[c][n] per
//     (b, 64-n tile).  Weights (bf16, preconverted by k0) staged via DMA with
//     XOR-slot swizzle -> LDS [192][128] (16 slots of 16B per row; ROUND-9
//     BUG was sizing this [192][64] -- half the K dim read garbage).
//     x tile transposed -> LDS bf16 x_t[64 n][136 c].  Epilogue: ot 0-3 ->
//     qk_t (QK_SCALE already folded); ot 4-7 -> xv_bf (+b_v); ot 8-11 -> xc.
// ---------------------------------------------------------------------------
__global__ __launch_bounds__(256) void k1_proj(
    const float* __restrict__ x, const unsigned short* __restrict__ wst,
    const float* __restrict__ b_v,
    unsigned short* __restrict__ qk_t, unsigned short* __restrict__ xv_bf,
    float* __restrict__ xc)
{
    __shared__ __align__(16) unsigned short w_lds[192 * 128];
    __shared__ __align__(16) unsigned short x_t[64 * 136];
    const int tid = threadIdx.x;
    const int wave = tid >> 6, lane = tid & 63;
    const int quad = lane >> 4, col = lane & 15;
    const int b = blockIdx.y;
    const int n0 = blockIdx.x * 64;

    // stage weights: 192 rows x 16 slots of 16B; src slot = seg ^ (row&7)
    // (XOR flips only low 3 bits -> bijective within the 16-slot row).
    // LDS dest = idx*16 B (lane-linear, required by global_load_lds).
    #pragma unroll
    for (int it = 0; it < 12; ++it) {
        const int idx = it * 256 + tid;                // [0, 3072)
        const int row = idx >> 4, seg = idx & 15;
        gl_lds16(wst + (size_t)row * 128 + (size_t)(seg ^ (row & 7)) * 8,
                 w_lds + idx * 8);
    }
    const float* xb = x + (size_t)b * C_ * N_ + n0;
    #pragma unroll
    for (int it = 0; it < 8; ++it) {
        const int idx = it * 256 + tid;                // [0, 2048)
        const int c = idx >> 4, n = (idx & 15) * 4;
        const float4 v = *(const float4*)(xb + (size_t)c * N_ + n);
        x_t[(n + 0) * 136 + c] = f2bf(v.x);
        x_t[(n + 1) * 136 + c] = f2bf(v.y);
        x_t[(n + 2) * 136 + c] = f2bf(v.z);
        x_t[(n + 3) * 136 + c] = f2bf(v.w);
    }
    __syncthreads();

    const int nw = wave * 16;
    bf16x8 bfr[4];
    #pragma unroll
    for (int kt = 0; kt < 4; ++kt)
        bfr[kt] = *(const bf16x8*)&x_t[(nw + col) * 136 + kt * 32 + quad * 8];

    const int n_g = n0 + nw + col;

    #pragma unroll
    for (int ot = 0; ot < 12; ++ot) {
        f32x4 acc = {0.f, 0.f, 0.f, 0.f};
        #pragma unroll
        for (int kt = 0; kt < 4; ++kt) {
            // row = ot*16+col -> row&7 == col&7; slot s=kt*4+quad read at s^(row&7)
            const bf16x8 afr = *(const bf16x8*)&w_lds[
                ((ot * 16 + col) << 7) + (((kt * 4 + quad) ^ (col & 7)) << 3)];
            acc = MFMA16(afr, bfr[kt], acc);
        }
        if (ot < 4) {
            us4 pk;
            pk.a = f2bf(acc[0]); pk.b = f2bf(acc[1]);
            pk.c = f2bf(acc[2]); pk.d = f2bf(acc[3]);
            *(us4*)&qk_t[(size_t)(b * N_ + n_g) * C2_ + ot * 16 + quad * 4] = pk;
        } else if (ot < 8) {
            const float4 bv4 = *(const float4*)(b_v + (ot - 4) * 16 + quad * 4);
            const float* bvp = (const float*)&bv4;
            #pragma unroll
            for (int r = 0; r < 4; ++r)
                xv_bf[(size_t)(b * C2_ + (ot - 4) * 16 + quad * 4 + r) * N_ + n_g]
                    = f2bf(acc[r] + bvp[r]);
        } else {
            #pragma unroll
            for (int r = 0; r < 4; ++r)
                xc[(size_t)(b * C2_ + (ot - 8) * 16 + quad * 4 + r) * N_ + n_g] = acc[r];
        }
    }
}

// ---------------------------------------------------------------------------
// K2: partial row softmax sums.  Grid 2048: b=id&7, nblk=(id>>3)&31, mq=id>>8.
//     Wave owns 32 n-rows (2 A-frag sets); block owns 128 rows x 512 m as
//     4 chunks of 128 m (2x16 KB dbuf).  part_rs[mq][b][n].
// ---------------------------------------------------------------------------
__global__ __launch_bounds__(256) void k2_rowstats(
    const unsigned short* __restrict__ qk_t, float* __restrict__ part_rs)
{
    __shared__ __align__(16) unsigned char lds_raw[2 * 16384];
    const int tid = threadIdx.x;
    const int wave = tid >> 6, lane = tid & 63;
    const int quad = lane >> 4, col = lane & 15;
    const int b = blockIdx.x & 7;
    const int nblk = (blockIdx.x >> 3) & 31;
    const int mq = blockIdx.x >> 8;                   // 0..7
    const int n_base = nblk * 128 + wave * 32;
    const int m_start = mq * 512;
    const unsigned short* qb = qk_t + (size_t)b * N_ * C2_;

    // two persistent A-frag sets: rows n_base + s*16 + col
    bf16x8 a0[2], a1[2];
    #pragma unroll
    for (int s = 0; s < 2; ++s) {
        const unsigned short* p = qb + (size_t)(n_base + s * 16 + col) * C2_ + quad * 8;
        a0[s] = *(const bf16x8*)p;
        a1[s] = *(const bf16x8*)(p + 32);
    }

    // stage 128 m-rows (16 KB) into buffer p
    auto stage = [&](int m0, int p) {
        unsigned char* base = lds_raw + p * 16384;
        #pragma unroll
        for (int r = 0; r < 4; ++r) {
            const int idx = r * 256 + tid;             // [0, 1024)
            const int row = idx >> 3, seg = idx & 7;
            gl_lds16(qb + (size_t)(m0 + row) * C2_ + (size_t)(seg ^ (row & 7)) * 8,
                     base + idx * 16);
        }
    };

    float run_s[2][4];
    #pragma unroll
    for (int s = 0; s < 2; ++s)
        #pragma unroll
        for (int r = 0; r < 4; ++r) run_s[s][r] = 0.f;

    stage(m_start, 0);

    for (int c = 0; c < 4; ++c) {
        const int p = c & 1;
        asm volatile("s_waitcnt vmcnt(0)" ::: "memory");   // prev stage landed (issued 1 chunk ago)
        __builtin_amdgcn_s_barrier();
        asm volatile("" ::: "memory");
        if (c + 1 < 4) stage(m_start + (c + 1) * 128, 1 - p);
        const unsigned short* qt = (const unsigned short*)(lds_raw + p * 16384);
        #pragma unroll
        for (int ms = 0; ms < 8; ++ms) {
            const int row = ms * 16 + col;
            const bf16x8 b0 = *(const bf16x8*)(qt + row * 64 + ((quad ^ (col & 7)) * 8));
            const bf16x8 b1 = *(const bf16x8*)(qt + row * 64 + (((4 + quad) ^ (col & 7)) * 8));
            #pragma unroll
            for (int s = 0; s < 2; ++s) {
                f32x4 acc = {0.f, 0.f, 0.f, 0.f};
                __builtin_amdgcn_s_setprio(1);
                acc = MFMA16(a0[s], b0, acc);
                acc = MFMA16(a1[s], b1, acc);
                __builtin_amdgcn_s_setprio(0);
                #pragma unroll
                for (int r = 0; r < 4; ++r)
                    run_s[s][r] += __builtin_amdgcn_exp2f(acc[r]);
            }
        }
    }

    #pragma unroll
    for (int s = 0; s < 2; ++s)
        #pragma unroll
        for (int r = 0; r < 4; ++r) {
            #pragma unroll
            for (int off = 1; off < 16; off <<= 1)
                run_s[s][r] += __shfl_xor(run_s[s][r], off, 64);
        }
    if (col == 0) {
        #pragma unroll
        for (int s = 0; s < 2; ++s)
            #pragma unroll
            for (int r = 0; r < 4; ++r)
                part_rs[((size_t)(mq * 8 + b) << 12) + n_base + s * 16 + quad * 4 + r]
                    = run_s[s][r];
    }
}

// ---------------------------------------------------------------------------
// K2w: winv[b][n] = 1 / sum_q part_rs[q][b][n].  Grid 512 x 64 threads.
//      (Replaces k2bc: xv is no longer pre-scaled -- k3 folds winv into S'.)
// ---------------------------------------------------------------------------
__global__ __launch_bounds__(64) void k2w(
    const float* __restrict__ part_rs, float* __restrict__ winv)
{
    const int b = blockIdx.x & 7;
    const int n = (blockIdx.x >> 3) * 64 + threadIdx.x;
    float s = 0.f;
    #pragma unroll
    for (int q = 0; q < 8; ++q)
        s += part_rs[((size_t)(q * 8 + b) << 12) + n];
    winv[b * N_ + n] = 1.0f / s;
}

// ---------------------------------------------------------------------------
// K3: R7-exact structure (measured 47.9us; best of 6 schedule variants) +
//     winv folded into S' in-register: S'' = winv[n] * exp2(E') packed to
//     bf16; PV uses RAW xv; colsum A-operand = ones.  DMA dbuf staging of
//     qk/xv, one __syncthreads per chunk, wave-private stS round-trip.
//     8-wave blocks, 32-m per wave, split-K=2, grid 512 = 2 blk/CU,
//     16 waves/CU.  launch_bounds(512,4): cap 128 >> natural ~105 ->
//     spill impossible (rounds-2/4 lesson).
// ---------------------------------------------------------------------------
__global__ __launch_bounds__(512, 4) void k3_pv(
    const unsigned short* __restrict__ qk_t, const unsigned short* __restrict__ xv_bf,
    const float* __restrict__ winv,
    unsigned short* __restrict__ yb0, unsigned short* __restrict__ yb1,
    float* __restrict__ cspart)
{
    // 0..16K: qk dbuf | 16K..32K: xv dbuf | 32K..52K: stS (8 waves x 2560 B)
    __shared__ __align__(16) unsigned char lds_raw[32768 + 8 * 2560];
    const int tid = threadIdx.x;
    const int wave = tid >> 6, lane = tid & 63;
    const int quad = lane >> 4, col = lane & 15;
    const int nh2 = wave & 1, mh = wave >> 1;        // mh 0..3
    const int b = blockIdx.x & 7;
    const int m_blk = ((blockIdx.x >> 3) & 31) * 128;
    const int sk = blockIdx.x >> 8;                  // 0..1 (split-K index)
    const int n_start = sk * 2048;
    const int n_chunks = 32;
    const int m_wave = m_blk + mh * 32;
    const unsigned short* qb = qk_t + (size_t)b * N_ * C2_;
    const unsigned short* vb = xv_bf + (size_t)b * C2_ * N_;
    const float* wn = winv + b * N_;
    unsigned short* yp = (sk == 0) ? yb0 : yb1;

    // persistent B-operands for E: this wave's 32 m-cols (2 groups of 16)
    bf16x8 kb0[2], kb1[2];
    #pragma unroll
    for (int g = 0; g < 2; ++g) {
        const unsigned short* p = qb + (size_t)(m_wave + g * 16 + col) * C2_ + quad * 8;
        kb0[g] = *(const bf16x8*)p;
        kb1[g] = *(const bf16x8*)(p + 32);
    }

    // colsum A-operand: constant ones (S'' already carries winv)
    bf16x8 ones;
    #pragma unroll
    for (int j = 0; j < 8; ++j) ones[j] = (__bf16)1.0f;

    unsigned short* stS = (unsigned short*)(lds_raw + 32768 + wave * 2560); // [g][col][40]

    // stage one 64n qk slab + 64ch xv tile (8 KB each): 1 DMA/lane/array
    auto stage = [&](int n0, int p) {
        unsigned char* qbase = lds_raw + p * 8192;
        unsigned char* vbase = lds_raw + 16384 + p * 8192;
        const int row = tid >> 3, seg = tid & 7;
        const int ss = seg ^ (row & 7);
        gl_lds16(qb + (size_t)(n0 + row) * C2_ + (size_t)ss * 8, qbase + tid * 16);
        gl_lds16(vb + (size_t)row * N_ + n0 + ss * 8, vbase + tid * 16);
    };

    f32x4 accY[2][4];   // [g][os]
    #pragma unroll
    for (int g = 0; g < 2; ++g)
        #pragma unroll
        for (int os = 0; os < 4; ++os) accY[g][os] = (f32x4){0.f, 0.f, 0.f, 0.f};
    f32x4 csacc[2];
    #pragma unroll
    for (int g = 0; g < 2; ++g) csacc[g] = (f32x4){0.f, 0.f, 0.f, 0.f};

    stage(n_start, 0);
    __syncthreads();

    for (int c = 0; c < n_chunks; ++c) {
        const int n0 = n_start + c * 64;
        const int p = c & 1;
        if (c + 1 < n_chunks) stage(n0 + 64, 1 - p);

        const unsigned short* qt = (const unsigned short*)(lds_raw + p * 8192);
        const unsigned short* vt = (const unsigned short*)(lds_raw + 16384 + p * 8192);

        // E phase over this wave's 32 n-rows; S'' = winv[n]*exp2(E') -> LDS
        #pragma unroll
        for (int ns = 0; ns < 2; ++ns) {
            const int row = nh2 * 32 + ns * 16 + col;
            const bf16x8 qa0 = *(const bf16x8*)(qt + row * 64 + ((quad ^ (col & 7)) * 8));
            const bf16x8 qa1 = *(const bf16x8*)(qt + row * 64 + (((4 + quad) ^ (col & 7)) * 8));
            const float4 wv4 = *(const float4*)(wn + n0 + nh2 * 32 + ns * 16 + quad * 4);
            const float* wv = (const float*)&wv4;
            #pragma unroll
            for (int g = 0; g < 2; ++g) {
                f32x4 acc = {0.f, 0.f, 0.f, 0.f};
                acc = MFMA16(qa0, kb0[g], acc);
                acc = MFMA16(qa1, kb1[g], acc);
                union { unsigned short us[4]; uint2 u2; } pk;
                #pragma unroll
                for (int r = 0; r < 4; ++r)
                    pk.us[r] = f2bf(wv[r] * __builtin_amdgcn_exp2f(acc[r]));
                *(uint2*)&stS[(g * 16 + col) * 40 + ns * 16 + quad * 4] = pk.u2;
            }
        }

        // same-wave round-trip: S'' as B-operand (K = this wave's 32 n)
        bf16x8 sB[2];
        #pragma unroll
        for (int g = 0; g < 2; ++g)
            sB[g] = *(const bf16x8*)&stS[(g * 16 + col) * 40 + quad * 8];

        // colsum via MFMA with A = ones -> D rows all = colsum of S''
        #pragma unroll
        for (int g = 0; g < 2; ++g)
            csacc[g] = MFMA16(ones, sB[g], csacc[g]);

        // PV: A = raw xv rows (o), k = this wave's 32 n
        #pragma unroll
        for (int os = 0; os < 4; ++os) {
            const bf16x8 va = *(const bf16x8*)(vt + (os * 16 + col) * 64 +
                                               (((nh2 * 4 + quad) ^ (col & 7)) * 8));
            #pragma unroll
            for (int g = 0; g < 2; ++g)
                accY[g][os] = MFMA16(va, sB[g], accY[g][os]);
        }
        __syncthreads();
    }

    // epilogue: combine the two n-halves (waves nh2=1 -> LDS; nh2=0 adds+writes)
    float* cmb = (float*)lds_raw;              // 32 KB: [mh][g*4+os][r][lane]
    float* csc = (float*)(lds_raw + 32768);    // 2 KB:  [mh][g][lane]
    if (nh2 == 1) {
        #pragma unroll
        for (int g = 0; g < 2; ++g) {
            #pragma unroll
            for (int os = 0; os < 4; ++os)
                #pragma unroll
                for (int r = 0; r < 4; ++r)
                    cmb[((mh * 8 + g * 4 + os) * 4 + r) * 64 + lane] = accY[g][os][r];
            csc[(mh * 2 + g) * 64 + lane] = csacc[g][0];
        }
    }
    __syncthreads();
    if (nh2 == 0) {
        #pragma unroll
        for (int g = 0; g < 2; ++g) {
            const float cs = csacc[g][0] + csc[(mh * 2 + g) * 64 + lane];
            if (lane < 16)
                cspart[((size_t)sk * 8 + b) * N_ + m_wave + g * 16 + lane] = cs;
            #pragma unroll
            for (int os = 0; os < 4; ++os)
                #pragma unroll
                for (int r = 0; r < 4; ++r) {
                    const float v = accY[g][os][r] +
                        cmb[((mh * 8 + g * 4 + os) * 4 + r) * 64 + lane];
                    yp[(size_t)(b * C2_ + os * 16 + quad * 4 + r) * N_ + m_wave + g * 16 + col]
                        = f2bf(v);
                }
        }
    }
}

// ---------------------------------------------------------------------------
// K4: fused partial-combine + w_t GEMM (MFMA) + BN partial stats.
//     Grid (64, 8), 64-n tiles.  cinv = 1/(eps+sum cspart over 2 splits);
//     d = xc - (y0+y1)*cinv (y partials BF16 -> 8 MB read) staged TRANSPOSED
//     to LDS bf16 d_t[n][72]; w_t staged bf16 [o][72].  Wave = o-tile; K=64.
//     t = acc + b_t -> t_buf; per-block channel partials -> part_bn[c][blk].
// ---------------------------------------------------------------------------
__global__ __launch_bounds__(256) void k4_t(
    const float* __restrict__ xc, const unsigned short* __restrict__ y0,
    const unsigned short* __restrict__ y1,
    const float* __restrict__ cspart, const float* __restrict__ w_t,
    const float* __restrict__ b_t, float* __restrict__ t_buf,
    float* __restrict__ part_bn)
{
    __shared__ __align__(16) unsigned short wlds[64 * 72];
    __shared__ __align__(16) unsigned short d_t[64 * 72];
    __shared__ float cinv[64];
    const int tid = threadIdx.x;
    const int wave = tid >> 6, lane = tid & 63;
    const int quad = lane >> 4, col = lane & 15;
    const int b = blockIdx.y;
    const int n0 = blockIdx.x * 64;
    const size_t base = (size_t)b * C2_ * N_;

    // phase 0: w_t -> bf16 LDS; per-n colsum inverse
    #pragma unroll
    for (int it = 0; it < 4; ++it) {
        const int idx4 = it * 256 + tid;               // [0, 1024)
        const int o = idx4 >> 4, i4 = (idx4 & 15) * 4;
        const float4 v = *(const float4*)(w_t + o * 64 + i4);
        us4 pk;
        pk.a = f2bf(v.x); pk.b = f2bf(v.y); pk.c = f2bf(v.z); pk.d = f2bf(v.w);
        *(us4*)&wlds[o * 72 + i4] = pk;
    }
    if (tid < 64) {
        const int n = n0 + tid;
        const float cs = cspart[(size_t)b * N_ + n] + cspart[(size_t)(8 + b) * N_ + n];
        cinv[tid] = 1.0f / (1e-9f + cs);
    }
    __syncthreads();

    // phase 1: d = xc - (y0+y1)*cinv, transposed bf16 -> d_t[n][i]
    #pragma unroll
    for (int it = 0; it < 4; ++it) {
        const int idx4 = it * 256 + tid;               // [0, 1024)
        const int i = idx4 >> 4, n4 = (idx4 & 15) * 4;
        const size_t g = base + (size_t)i * N_ + n0 + n4;
        const float4 c4 = *(const float4*)(xc + g);
        const us4 u0 = *(const us4*)(y0 + g);
        const us4 u1 = *(const us4*)(y1 + g);
        d_t[(n4 + 0) * 72 + i] = f2bf(c4.x - (bf2f(u0.a) + bf2f(u1.a)) * cinv[n4 + 0]);
        d_t[(n4 + 1) * 72 + i] = f2bf(c4.y - (bf2f(u0.b) + bf2f(u1.b)) * cinv[n4 + 1]);
        d_t[(n4 + 2) * 72 + i] = f2bf(c4.z - (bf2f(u0.c) + bf2f(u1.c)) * cinv[n4 + 2]);
        d_t[(n4 + 3) * 72 + i] = f2bf(c4.w - (bf2f(u0.d) + bf2f(u1.d)) * cinv[n4 + 3]);
    }
    __syncthreads();

    const int ow = wave * 16;
    bf16x8 afr[2];
    #pragma unroll
    for (int kt = 0; kt < 2; ++kt)
        afr[kt] = *(const bf16x8*)&wlds[(ow + col) * 72 + kt * 32 + quad * 8];
    const float4 bt4 = *(const float4*)(b_t + ow + quad * 4);
    const float* btp = (const float*)&bt4;

    float s[4] = {0.f, 0.f, 0.f, 0.f}, q2[4] = {0.f, 0.f, 0.f, 0.f};
    #pragma unroll
    for (int ns = 0; ns < 4; ++ns) {
        f32x4 acc = {0.f, 0.f, 0.f, 0.f};
        #pragma unroll
        for (int kt = 0; kt < 2; ++kt) {
            const bf16x8 bfr = *(const bf16x8*)&d_t[(ns * 16 + col) * 72 + kt * 32 + quad * 8];
            acc = MFMA16(afr[kt], bfr, acc);
        }
        #pragma unroll
        for (int r = 0; r < 4; ++r) {
            const float t = acc[r] + btp[r];
            t_buf[base + (size_t)(ow + quad * 4 + r) * N_ + n0 + ns * 16 + col] = t;
            s[r] += t;
            q2[r] += t * t;
        }
    }
    #pragma unroll
    for (int r = 0; r < 4; ++r) {
        #pragma unroll
        for (int off = 1; off < 16; off <<= 1) {
            s[r]  += __shfl_xor(s[r],  off, 64);
            q2[r] += __shfl_xor(q2[r], off, 64);
        }
    }
    if (col == 0) {
        const int blk = blockIdx.x * 8 + b;            // [0, 512)
        #pragma unroll
        for (int r = 0; r < 4; ++r) {
            part_bn[(size_t)(ow + quad * 4 + r) * 512 + blk]      = s[r];
            part_bn[(size_t)(64 + ow + quad * 4 + r) * 512 + blk] = q2[r];
        }
    }
}

// K5r: bn[c] = sum_blk part_bn[c][blk], c in [0,128)
__global__ __launch_bounds__(256) void k5r(
    const float* __restrict__ part_bn, float* __restrict__ bn)
{
    const int c = blockIdx.x;
    const int tid = threadIdx.x, wave = tid >> 6, lane = tid & 63;
    float s = 0.f;
    for (int j = tid; j < 512; j += 256) s += part_bn[(size_t)c * 512 + j];
    #pragma unroll
    for (int off = 1; off < 64; off <<= 1) s += __shfl_xor(s, off, 64);
    __shared__ float red[4];
    if (lane == 0) red[wave] = s;
    __syncthreads();
    if (tid == 0) bn[c] = red[0] + red[1] + red[2] + red[3];
}

// ---------------------------------------------------------------------------
// K6: out = xc + relu(gamma * (t - mean) * rsqrt(var + eps) + beta)
// ---------------------------------------------------------------------------
__global__ __launch_bounds__(256) void k6_out(
    const float* __restrict__ xc, const float* __restrict__ t_buf,
    const float* __restrict__ bn, const float* __restrict__ gamma,
    const float* __restrict__ beta, float* __restrict__ out)
{
    const int idx = blockIdx.x * 256 + threadIdx.x;
    const int o = (idx >> 10) & 63;
    const float invC = 1.0f / (float)(B_ * N_);
    const float mean = bn[o] * invC;
    const float var  = bn[64 + o] * invC - mean * mean;
    const float sc = gamma[o] * rsqrtf(var + 1e-5f);
    const float sh = beta[o] - mean * sc;
    const float4 t4 = ((const float4*)t_buf)[idx];
    const float4 c4 = ((const float4*)xc)[idx];
    float4 r;
    r.x = c4.x + fmaxf(0.f, sc * t4.x + sh);
    r.y = c4.y + fmaxf(0.f, sc * t4.y + sh);
    r.z = c4.z + fmaxf(0.f, sc * t4.z + sh);
    r.w = c4.w + fmaxf(0.f, sc * t4.w + sh);
    ((float4*)out)[idx] = r;
}

extern "C" void kernel_launch(void* const* d_in, const int* in_sizes, int n_in,
                              void* d_out, int out_size, void* d_ws, size_t ws_size,
                              hipStream_t stream) {
    const float* x     = (const float*)d_in[0];
    const float* w_qk  = (const float*)d_in[1];
    const float* w_v   = (const float*)d_in[2];
    const float* b_v   = (const float*)d_in[3];
    const float* w_x   = (const float*)d_in[4];
    const float* w_t   = (const float*)d_in[5];
    const float* b_t   = (const float*)d_in[6];
    const float* gamma = (const float*)d_in[7];
    const float* beta  = (const float*)d_in[8];
    float* out = (float*)d_out;

    char* ws = (char*)d_ws;
    unsigned short* qk_t  = (unsigned short*)ws;                      // 4 MB
    unsigned short* xv_bf = (unsigned short*)(ws + (4  << 20));       // 4 MB
    float* xc      = (float*)(ws + (8  << 20));                       // 8 MB
    unsigned short* yb0 = (unsigned short*)(ws + (16 << 20));         // 4 MB (bf16 partial Y)
    unsigned short* yb1 = (unsigned short*)(ws + (20 << 20));         // 4 MB (bf16 partial Y)
    float* t_buf   = (float*)(ws + (24 << 20));                       // 8 MB
    float* part_rs = (float*)(ws + (32 << 20));                       // 1 MB (k2 -> k2w)
    float* cspart  = (float*)(ws + (32 << 20));                       // 256 KB (k3 -> k4; reuses part_rs)
    float* part_bn = (float*)(ws + (33 << 20));                       // 256 KB
    float* bn      = (float*)(ws + (33 << 20) + (256 << 10));         // 512 B
    // d_out doubles as scratch until k6 (k6 is the only writer of out):
    unsigned short* wstack = (unsigned short*)d_out;                  // 48 KB (k0 -> k1)
    float* winv = (float*)((char*)d_out + (256 << 10));               // 128 KB (k2w -> k3)

    hipLaunchKernelGGL(k0_wcvt,     dim3(24),     256, 0, stream, w_qk, w_v, w_x, wstack);
    hipLaunchKernelGGL(k1_proj,     dim3(64, 8),  256, 0, stream,
                       x, wstack, b_v, qk_t, xv_bf, xc);
    hipLaunchKernelGGL(k2_rowstats, dim3(2048),   256, 0, stream, qk_t, part_rs);
    hipLaunchKernelGGL(k2w,         dim3(512),    64,  0, stream, part_rs, winv);
    hipLaunchKernelGGL(k3_pv,       dim3(512),    512, 0, stream,
                       qk_t, xv_bf, winv, yb0, yb1, cspart);
    hipLaunchKernelGGL(k4_t,        dim3(64, 8),  256, 0, stream,
                       xc, yb0, yb1, cspart, w_t, b_t, t_buf, part_bn);
    hipLaunchKernelGGL(k5r,         dim3(128),    256, 0, stream, part_bn, bn);
    hipLaunchKernelGGL(k6_out,      dim3(2048),   256, 0, stream, xc, t_buf, bn, gamma, beta, out);
}

// Round 11
// 167.744 us; speedup vs baseline: 1.0150x; 1.0049x over previous
//
#include <hip/hip_runtime.h>

#define B_   8
#define C_   128
#define N_   4096
#define C2_  64

typedef __bf16 bf16x8 __attribute__((ext_vector_type(8)));
typedef float  f32x4  __attribute__((ext_vector_type(4)));

#define MFMA16(a, b, c) __builtin_amdgcn_mfma_f32_16x16x32_bf16((a), (b), (c), 0, 0, 0)

// sqrt(log2(e)): folded into w_qk by k0 so softmax uses exp2 directly
#define QK_SCALE 1.2011224087864498f

static __device__ __forceinline__ unsigned short f2bf(float f) {
    union { __bf16 b; unsigned short u; } cv;
    cv.b = (__bf16)f;
    return cv.u;
}
static __device__ __forceinline__ float bf2f(unsigned short u) {
    union { unsigned int u; float f; } cv;
    cv.u = ((unsigned int)u) << 16;
    return cv.f;
}

struct us4 { unsigned short a, b, c, d; };

// async global->LDS, 16 B per lane.  LDS dest must be linear in lane order.
static __device__ __forceinline__ void gl_lds16(const unsigned short* g, void* l) {
    __builtin_amdgcn_global_load_lds(
        (const __attribute__((address_space(1))) unsigned int*)g,
        (__attribute__((address_space(3))) unsigned int*)l,
        16, 0, 0);
}

// ---------------------------------------------------------------------------
// K0: one-time weight convert f32 -> bf16, stacked [w_qk; w_v; w_x] = [192][128].
//     QK_SCALE folded into w_qk rows.  24576 elems, grid 24 x 256 x 4.
// ---------------------------------------------------------------------------
__global__ __launch_bounds__(256) void k0_wcvt(
    const float* __restrict__ wq, const float* __restrict__ wv,
    const float* __restrict__ wx, unsigned short* __restrict__ wst)
{
    const int i4 = (blockIdx.x * 256 + threadIdx.x) * 4;   // [0, 24576)
    const int mat = i4 >> 13;                              // 8192 elems / matrix
    const float* src = (mat == 0) ? wq : (mat == 1) ? wv : wx;
    const float sc = (mat == 0) ? QK_SCALE : 1.0f;
    const float4 v = *(const float4*)(src + (i4 & 8191));
    us4 pk;
    pk.a = f2bf(v.x * sc); pk.b = f2bf(v.y * sc);
    pk.c = f2bf(v.z * sc); pk.d = f2bf(v.w * sc);
    *(us4*)(wst + i4) = pk;
}

// ---------------------------------------------------------------------------
// K1: fused projection GEMM.  D[192 o][64 n] = Wst[o][c] * x[c][n] per
//     (b, 64-n tile).  Weights (bf16 from k0) DMA-staged XOR-swizzled ->
//     LDS [192][128]; x tile transposed -> LDS bf16 x_t[64 n][136 c].
//     Epilogue: ot 0-3 -> qk_t; ot 4-7 -> xv_bf (+b_v); ot 8-11 -> xc (f32).
// ---------------------------------------------------------------------------
__global__ __launch_bounds__(256) void k1_proj(
    const float* __restrict__ x, const unsigned short* __restrict__ wst,
    const float* __restrict__ b_v,
    unsigned short* __restrict__ qk_t, unsigned short* __restrict__ xv_bf,
    float* __restrict__ xc)
{
    __shared__ __align__(16) unsigned short w_lds[192 * 128];
    __shared__ __align__(16) unsigned short x_t[64 * 136];
    const int tid = threadIdx.x;
    const int wave = tid >> 6, lane = tid & 63;
    const int quad = lane >> 4, col = lane & 15;
    const int b = blockIdx.y;
    const int n0 = blockIdx.x * 64;

    #pragma unroll
    for (int it = 0; it < 12; ++it) {
        const int idx = it * 256 + tid;                // [0, 3072)
        const int row = idx >> 4, seg = idx & 15;
        gl_lds16(wst + (size_t)row * 128 + (size_t)(seg ^ (row & 7)) * 8,
                 w_lds + idx * 8);
    }
    const float* xb = x + (size_t)b * C_ * N_ + n0;
    #pragma unroll
    for (int it = 0; it < 8; ++it) {
        const int idx = it * 256 + tid;                // [0, 2048)
        const int c = idx >> 4, n = (idx & 15) * 4;
        const float4 v = *(const float4*)(xb + (size_t)c * N_ + n);
        x_t[(n + 0) * 136 + c] = f2bf(v.x);
        x_t[(n + 1) * 136 + c] = f2bf(v.y);
        x_t[(n + 2) * 136 + c] = f2bf(v.z);
        x_t[(n + 3) * 136 + c] = f2bf(v.w);
    }
    __syncthreads();

    const int nw = wave * 16;
    bf16x8 bfr[4];
    #pragma unroll
    for (int kt = 0; kt < 4; ++kt)
        bfr[kt] = *(const bf16x8*)&x_t[(nw + col) * 136 + kt * 32 + quad * 8];

    const int n_g = n0 + nw + col;

    #pragma unroll
    for (int ot = 0; ot < 12; ++ot) {
        f32x4 acc = {0.f, 0.f, 0.f, 0.f};
        #pragma unroll
        for (int kt = 0; kt < 4; ++kt) {
            const bf16x8 afr = *(const bf16x8*)&w_lds[
                ((ot * 16 + col) << 7) + (((kt * 4 + quad) ^ (col & 7)) << 3)];
            acc = MFMA16(afr, bfr[kt], acc);
        }
        if (ot < 4) {
            us4 pk;
            pk.a = f2bf(acc[0]); pk.b = f2bf(acc[1]);
            pk.c = f2bf(acc[2]); pk.d = f2bf(acc[3]);
            *(us4*)&qk_t[(size_t)(b * N_ + n_g) * C2_ + ot * 16 + quad * 4] = pk;
        } else if (ot < 8) {
            const float4 bv4 = *(const float4*)(b_v + (ot - 4) * 16 + quad * 4);
            const float* bvp = (const float*)&bv4;
            #pragma unroll
            for (int r = 0; r < 4; ++r)
                xv_bf[(size_t)(b * C2_ + (ot - 4) * 16 + quad * 4 + r) * N_ + n_g]
                    = f2bf(acc[r] + bvp[r]);
        } else {
            #pragma unroll
            for (int r = 0; r < 4; ++r)
                xc[(size_t)(b * C2_ + (ot - 8) * 16 + quad * 4 + r) * N_ + n_g] = acc[r];
        }
    }
}

// ---------------------------------------------------------------------------
// K2_sym: partial row softmax sums exploiting E symmetry.  q and k share
//     w_qk => E[n][m] = qk[n].qk[m] is SYMMETRIC, so only tiles ti<=tj of
//     the 32x32 (128-wide) tile grid are computed: 528/1024 = 51.6% of the
//     E-GEMM+exp2 work.  Off-diagonal tile (ti,tj) contributes its ROW sums
//     to range ti (slot tj) and its COLUMN sums to range tj (slot ti);
//     diagonal contributes rows only (slot ti).  Every (slot,range) pair is
//     written exactly once -> no atomics, no zeroing.  part_rs[32][8][4096].
//     A-frags direct-global; B staged XOR-swizzled (both verbatim old-k2
//     patterns).  Grid 4224 = 528 jobs x 8 b (id&7=b for XCD locality).
// ---------------------------------------------------------------------------
__global__ __launch_bounds__(256) void k2_sym(
    const unsigned short* __restrict__ qk_t, float* __restrict__ part_rs)
{
    __shared__ __align__(16) unsigned short slab[128 * 64];
    __shared__ float cwl[4 * 128];
    const int tid = threadIdx.x;
    const int wave = tid >> 6, lane = tid & 63;
    const int quad = lane >> 4, col = lane & 15;
    const int b = blockIdx.x & 7;
    int job = blockIdx.x >> 3, ti = 0;                 // job in [0,528)
    while (job >= 32 - ti) { job -= 32 - ti; ++ti; }
    const int tj = ti + job;
    const unsigned short* qb = qk_t + (size_t)b * N_ * C2_;

    // A-frags: this wave's 32 n-rows of tile ti (direct global)
    const int n_base = ti * 128 + wave * 32;
    bf16x8 a0[2], a1[2];
    #pragma unroll
    for (int s = 0; s < 2; ++s) {
        const unsigned short* p = qb + (size_t)(n_base + s * 16 + col) * C2_ + quad * 8;
        a0[s] = *(const bf16x8*)p;
        a1[s] = *(const bf16x8*)(p + 32);
    }

    // stage tile tj's 128 rows (16 KB), XOR-slot swizzled
    #pragma unroll
    for (int r = 0; r < 4; ++r) {
        const int idx = r * 256 + tid;                 // [0, 1024)
        const int row = idx >> 3, seg = idx & 7;
        gl_lds16(qb + (size_t)(tj * 128 + row) * C2_ + (size_t)(seg ^ (row & 7)) * 8,
                 slab + idx * 8);
    }
    __syncthreads();

    float run_s[2][4];
    #pragma unroll
    for (int s = 0; s < 2; ++s)
        #pragma unroll
        for (int r = 0; r < 4; ++r) run_s[s][r] = 0.f;

    #pragma unroll
    for (int g = 0; g < 8; ++g) {
        const int row = g * 16 + col;
        const bf16x8 b0 = *(const bf16x8*)(slab + row * 64 + ((quad ^ (col & 7)) * 8));
        const bf16x8 b1 = *(const bf16x8*)(slab + row * 64 + (((4 + quad) ^ (col & 7)) * 8));
        float cs = 0.f;
        #pragma unroll
        for (int s = 0; s < 2; ++s) {
            f32x4 acc = {0.f, 0.f, 0.f, 0.f};
            __builtin_amdgcn_s_setprio(1);
            acc = MFMA16(a0[s], b0, acc);
            acc = MFMA16(a1[s], b1, acc);
            __builtin_amdgcn_s_setprio(0);
            #pragma unroll
            for (int r = 0; r < 4; ++r) {
                const float u = __builtin_amdgcn_exp2f(acc[r]);
                run_s[s][r] += u;                      // row-sum side (m summed)
                cs += u;                               // col-sum side (n summed)
            }
        }
        // colsum over this wave's 32 n: in-register (s,r) done; cross-quad:
        cs += __shfl_xor(cs, 16, 64);
        cs += __shfl_xor(cs, 32, 64);
        if (quad == 0) cwl[wave * 128 + g * 16 + col] = cs;
    }
    __syncthreads();
    if (ti != tj && tid < 128) {
        const float c = cwl[tid] + cwl[128 + tid] + cwl[256 + tid] + cwl[384 + tid];
        part_rs[((size_t)(ti * 8 + b) << 12) + tj * 128 + tid] = c;
    }

    // row-sum finalize: reduce over the 16 col lanes
    #pragma unroll
    for (int s = 0; s < 2; ++s)
        #pragma unroll
        for (int r = 0; r < 4; ++r) {
            #pragma unroll
            for (int off = 1; off < 16; off <<= 1)
                run_s[s][r] += __shfl_xor(run_s[s][r], off, 64);
        }
    if (col == 0) {
        #pragma unroll
        for (int s = 0; s < 2; ++s)
            #pragma unroll
            for (int r = 0; r < 4; ++r)
                part_rs[((size_t)(tj * 8 + b) << 12) + n_base + s * 16 + quad * 4 + r]
                    = run_s[s][r];
    }
}

// ---------------------------------------------------------------------------
// K2w: lw[b][n] = -log2( sum_{t<32} part_rs[t][b][n] ).  Grid 512 x 64.
//      k3 folds lw into the E MFMA's C-operand: exp2(E+lw) = exp2(E)/rowsum.
// ---------------------------------------------------------------------------
__global__ __launch_bounds__(64) void k2w(
    const float* __restrict__ part_rs, float* __restrict__ lw)
{
    const int b = blockIdx.x & 7;
    const int n = (blockIdx.x >> 3) * 64 + threadIdx.x;
    float s = 0.f;
    #pragma unroll
    for (int t = 0; t < 32; ++t)
        s += part_rs[((size_t)(t * 8 + b) << 12) + n];
    lw[b * N_ + n] = -__log2f(s);
}

// ---------------------------------------------------------------------------
// K3: R7-exact structure + lw folded via the MFMA C-operand (ZERO extra
//     VALU vs R7's E-phase; R10's mul-fold cost 4us): acc init = lw4,
//     S'' = exp2(E+lw) = winv*exp2(E) packed bf16; PV uses RAW xv; colsum
//     A = ones.  DMA dbuf staging, 1 barrier/chunk, wave-private stS.
//     8 waves, 32-m/wave, split-K=2, grid 512 = 2 blk/CU, 16 waves/CU.
//     launch_bounds(512,4): cap 128 >> natural ~105 -> no spill.
// ---------------------------------------------------------------------------
__global__ __launch_bounds__(512, 4) void k3_pv(
    const unsigned short* __restrict__ qk_t, const unsigned short* __restrict__ xv_bf,
    const float* __restrict__ lw,
    unsigned short* __restrict__ yb0, unsigned short* __restrict__ yb1,
    float* __restrict__ cspart)
{
    // 0..16K: qk dbuf | 16K..32K: xv dbuf | 32K..52K: stS (8 waves x 2560 B)
    __shared__ __align__(16) unsigned char lds_raw[32768 + 8 * 2560];
    const int tid = threadIdx.x;
    const int wave = tid >> 6, lane = tid & 63;
    const int quad = lane >> 4, col = lane & 15;
    const int nh2 = wave & 1, mh = wave >> 1;        // mh 0..3
    const int b = blockIdx.x & 7;
    const int m_blk = ((blockIdx.x >> 3) & 31) * 128;
    const int sk = blockIdx.x >> 8;                  // 0..1 (split-K index)
    const int n_start = sk * 2048;
    const int n_chunks = 32;
    const int m_wave = m_blk + mh * 32;
    const unsigned short* qb = qk_t + (size_t)b * N_ * C2_;
    const unsigned short* vb = xv_bf + (size_t)b * C2_ * N_;
    const float* ln = lw + b * N_;
    unsigned short* yp = (sk == 0) ? yb0 : yb1;

    // persistent B-operands for E: this wave's 32 m-cols (2 groups of 16)
    bf16x8 kb0[2], kb1[2];
    #pragma unroll
    for (int g = 0; g < 2; ++g) {
        const unsigned short* p = qb + (size_t)(m_wave + g * 16 + col) * C2_ + quad * 8;
        kb0[g] = *(const bf16x8*)p;
        kb1[g] = *(const bf16x8*)(p + 32);
    }

    // colsum A-operand: constant ones (S'' already carries the row scale)
    bf16x8 ones;
    #pragma unroll
    for (int j = 0; j < 8; ++j) ones[j] = (__bf16)1.0f;

    unsigned short* stS = (unsigned short*)(lds_raw + 32768 + wave * 2560); // [g][col][40]

    // stage one 64n qk slab + 64ch xv tile (8 KB each): 1 DMA/lane/array
    auto stage = [&](int n0, int p) {
        unsigned char* qbase = lds_raw + p * 8192;
        unsigned char* vbase = lds_raw + 16384 + p * 8192;
        const int row = tid >> 3, seg = tid & 7;
        const int ss = seg ^ (row & 7);
        gl_lds16(qb + (size_t)(n0 + row) * C2_ + (size_t)ss * 8, qbase + tid * 16);
        gl_lds16(vb + (size_t)row * N_ + n0 + ss * 8, vbase + tid * 16);
    };

    f32x4 accY[2][4];   // [g][os]
    #pragma unroll
    for (int g = 0; g < 2; ++g)
        #pragma unroll
        for (int os = 0; os < 4; ++os) accY[g][os] = (f32x4){0.f, 0.f, 0.f, 0.f};
    f32x4 csacc[2];
    #pragma unroll
    for (int g = 0; g < 2; ++g) csacc[g] = (f32x4){0.f, 0.f, 0.f, 0.f};

    stage(n_start, 0);
    __syncthreads();

    for (int c = 0; c < n_chunks; ++c) {
        const int n0 = n_start + c * 64;
        const int p = c & 1;
        if (c + 1 < n_chunks) stage(n0 + 64, 1 - p);

        const unsigned short* qt = (const unsigned short*)(lds_raw + p * 8192);
        const unsigned short* vt = (const unsigned short*)(lds_raw + 16384 + p * 8192);

        // E phase; S'' = exp2(E + lw[n]) -> LDS (lw enters as MFMA C-init)
        #pragma unroll
        for (int ns = 0; ns < 2; ++ns) {
            const int row = nh2 * 32 + ns * 16 + col;
            const bf16x8 qa0 = *(const bf16x8*)(qt + row * 64 + ((quad ^ (col & 7)) * 8));
            const bf16x8 qa1 = *(const bf16x8*)(qt + row * 64 + (((4 + quad) ^ (col & 7)) * 8));
            const float4 lw4 = *(const float4*)(ln + n0 + nh2 * 32 + ns * 16 + quad * 4);
            #pragma unroll
            for (int g = 0; g < 2; ++g) {
                f32x4 acc = {lw4.x, lw4.y, lw4.z, lw4.w};
                acc = MFMA16(qa0, kb0[g], acc);
                acc = MFMA16(qa1, kb1[g], acc);
                union { unsigned short us[4]; uint2 u2; } pk;
                #pragma unroll
                for (int r = 0; r < 4; ++r)
                    pk.us[r] = f2bf(__builtin_amdgcn_exp2f(acc[r]));
                *(uint2*)&stS[(g * 16 + col) * 40 + ns * 16 + quad * 4] = pk.u2;
            }
        }

        // same-wave round-trip: S'' as B-operand (K = this wave's 32 n)
        bf16x8 sB[2];
        #pragma unroll
        for (int g = 0; g < 2; ++g)
            sB[g] = *(const bf16x8*)&stS[(g * 16 + col) * 40 + quad * 8];

        // colsum via MFMA with A = ones -> D rows all = colsum of S''
        #pragma unroll
        for (int g = 0; g < 2; ++g)
            csacc[g] = MFMA16(ones, sB[g], csacc[g]);

        // PV: A = raw xv rows (o), k = this wave's 32 n
        #pragma unroll
        for (int os = 0; os < 4; ++os) {
            const bf16x8 va = *(const bf16x8*)(vt + (os * 16 + col) * 64 +
                                               (((nh2 * 4 + quad) ^ (col & 7)) * 8));
            #pragma unroll
            for (int g = 0; g < 2; ++g)
                accY[g][os] = MFMA16(va, sB[g], accY[g][os]);
        }
        __syncthreads();
    }

    // epilogue: combine the two n-halves (waves nh2=1 -> LDS; nh2=0 adds+writes)
    float* cmb = (float*)lds_raw;              // 32 KB: [mh][g*4+os][r][lane]
    float* csc = (float*)(lds_raw + 32768);    // 2 KB:  [mh][g][lane]
    if (nh2 == 1) {
        #pragma unroll
        for (int g = 0; g < 2; ++g) {
            #pragma unroll
            for (int os = 0; os < 4; ++os)
                #pragma unroll
                for (int r = 0; r < 4; ++r)
                    cmb[((mh * 8 + g * 4 + os) * 4 + r) * 64 + lane] = accY[g][os][r];
            csc[(mh * 2 + g) * 64 + lane] = csacc[g][0];
        }
    }
    __syncthreads();
    if (nh2 == 0) {
        #pragma unroll
        for (int g = 0; g < 2; ++g) {
            const float cs = csacc[g][0] + csc[(mh * 2 + g) * 64 + lane];
            if (lane < 16)
                cspart[((size_t)sk * 8 + b) * N_ + m_wave + g * 16 + lane] = cs;
            #pragma unroll
            for (int os = 0; os < 4; ++os)
                #pragma unroll
                for (int r = 0; r < 4; ++r) {
                    const float v = accY[g][os][r] +
                        cmb[((mh * 8 + g * 4 + os) * 4 + r) * 64 + lane];
                    yp[(size_t)(b * C2_ + os * 16 + quad * 4 + r) * N_ + m_wave + g * 16 + col]
                        = f2bf(v);
                }
        }
    }
}

// ---------------------------------------------------------------------------
// K4: fused partial-combine + w_t GEMM (MFMA) + BN partial stats.
//     Grid (64, 8), 64-n tiles.  cinv = 1/(eps+sum cspart over 2 splits);
//     d = xc - (y0+y1)*cinv staged TRANSPOSED to LDS bf16 d_t[n][72];
//     w_t staged bf16 [o][72].  Wave = o-tile; K=64.  t -> t_buf;
//     per-block channel partials -> part_bn[c][blk].
// ---------------------------------------------------------------------------
__global__ __launch_bounds__(256) void k4_t(
    const float* __restrict__ xc, const unsigned short* __restrict__ y0,
    const unsigned short* __restrict__ y1,
    const float* __restrict__ cspart, const float* __restrict__ w_t,
    const float* __restrict__ b_t, float* __restrict__ t_buf,
    float* __restrict__ part_bn)
{
    __shared__ __align__(16) unsigned short wlds[64 * 72];
    __shared__ __align__(16) unsigned short d_t[64 * 72];
    __shared__ float cinv[64];
    const int tid = threadIdx.x;
    const int wave = tid >> 6, lane = tid & 63;
    const int quad = lane >> 4, col = lane & 15;
    const int b = blockIdx.y;
    const int n0 = blockIdx.x * 64;
    const size_t base = (size_t)b * C2_ * N_;

    #pragma unroll
    for (int it = 0; it < 4; ++it) {
        const int idx4 = it * 256 + tid;               // [0, 1024)
        const int o = idx4 >> 4, i4 = (idx4 & 15) * 4;
        const float4 v = *(const float4*)(w_t + o * 64 + i4);
        us4 pk;
        pk.a = f2bf(v.x); pk.b = f2bf(v.y); pk.c = f2bf(v.z); pk.d = f2bf(v.w);
        *(us4*)&wlds[o * 72 + i4] = pk;
    }
    if (tid < 64) {
        const int n = n0 + tid;
        const float cs = cspart[(size_t)b * N_ + n] + cspart[(size_t)(8 + b) * N_ + n];
        cinv[tid] = 1.0f / (1e-9f + cs);
    }
    __syncthreads();

    #pragma unroll
    for (int it = 0; it < 4; ++it) {
        const int idx4 = it * 256 + tid;               // [0, 1024)
        const int i = idx4 >> 4, n4 = (idx4 & 15) * 4;
        const size_t g = base + (size_t)i * N_ + n0 + n4;
        const float4 c4 = *(const float4*)(xc + g);
        const us4 u0 = *(const us4*)(y0 + g);
        const us4 u1 = *(const us4*)(y1 + g);
        d_t[(n4 + 0) * 72 + i] = f2bf(c4.x - (bf2f(u0.a) + bf2f(u1.a)) * cinv[n4 + 0]);
        d_t[(n4 + 1) * 72 + i] = f2bf(c4.y - (bf2f(u0.b) + bf2f(u1.b)) * cinv[n4 + 1]);
        d_t[(n4 + 2) * 72 + i] = f2bf(c4.z - (bf2f(u0.c) + bf2f(u1.c)) * cinv[n4 + 2]);
        d_t[(n4 + 3) * 72 + i] = f2bf(c4.w - (bf2f(u0.d) + bf2f(u1.d)) * cinv[n4 + 3]);
    }
    __syncthreads();

    const int ow = wave * 16;
    bf16x8 afr[2];
    #pragma unroll
    for (int kt = 0; kt < 2; ++kt)
        afr[kt] = *(const bf16x8*)&wlds[(ow + col) * 72 + kt * 32 + quad * 8];
    const float4 bt4 = *(const float4*)(b_t + ow + quad * 4);
    const float* btp = (const float*)&bt4;

    float s[4] = {0.f, 0.f, 0.f, 0.f}, q2[4] = {0.f, 0.f, 0.f, 0.f};
    #pragma unroll
    for (int ns = 0; ns < 4; ++ns) {
        f32x4 acc = {0.f, 0.f, 0.f, 0.f};
        #pragma unroll
        for (int kt = 0; kt < 2; ++kt) {
            const bf16x8 bfr = *(const bf16x8*)&d_t[(ns * 16 + col) * 72 + kt * 32 + quad * 8];
            acc = MFMA16(afr[kt], bfr, acc);
        }
        #pragma unroll
        for (int r = 0; r < 4; ++r) {
            const float t = acc[r] + btp[r];
            t_buf[base + (size_t)(ow + quad * 4 + r) * N_ + n0 + ns * 16 + col] = t;
            s[r] += t;
            q2[r] += t * t;
        }
    }
    #pragma unroll
    for (int r = 0; r < 4; ++r) {
        #pragma unroll
        for (int off = 1; off < 16; off <<= 1) {
            s[r]  += __shfl_xor(s[r],  off, 64);
            q2[r] += __shfl_xor(q2[r], off, 64);
        }
    }
    if (col == 0) {
        const int blk = blockIdx.x * 8 + b;            // [0, 512)
        #pragma unroll
        for (int r = 0; r < 4; ++r) {
            part_bn[(size_t)(ow + quad * 4 + r) * 512 + blk]      = s[r];
            part_bn[(size_t)(64 + ow + quad * 4 + r) * 512 + blk] = q2[r];
        }
    }
}

// K5r: bn[c] = sum_blk part_bn[c][blk], c in [0,128)
__global__ __launch_bounds__(256) void k5r(
    const float* __restrict__ part_bn, float* __restrict__ bn)
{
    const int c = blockIdx.x;
    const int tid = threadIdx.x, wave = tid >> 6, lane = tid & 63;
    float s = 0.f;
    for (int j = tid; j < 512; j += 256) s += part_bn[(size_t)c * 512 + j];
    #pragma unroll
    for (int off = 1; off < 64; off <<= 1) s += __shfl_xor(s, off, 64);
    __shared__ float red[4];
    if (lane == 0) red[wave] = s;
    __syncthreads();
    if (tid == 0) bn[c] = red[0] + red[1] + red[2] + red[3];
}

// ---------------------------------------------------------------------------
// K6: out = xc + relu(gamma * (t - mean) * rsqrt(var + eps) + beta)
// ---------------------------------------------------------------------------
__global__ __launch_bounds__(256) void k6_out(
    const float* __restrict__ xc, const float* __restrict__ t_buf,
    const float* __restrict__ bn, const float* __restrict__ gamma,
    const float* __restrict__ beta, float* __restrict__ out)
{
    const int idx = blockIdx.x * 256 + threadIdx.x;
    const int o = (idx >> 10) & 63;
    const float invC = 1.0f / (float)(B_ * N_);
    const float mean = bn[o] * invC;
    const float var  = bn[64 + o] * invC - mean * mean;
    const float sc = gamma[o] * rsqrtf(var + 1e-5f);
    const float sh = beta[o] - mean * sc;
    const float4 t4 = ((const float4*)t_buf)[idx];
    const float4 c4 = ((const float4*)xc)[idx];
    float4 r;
    r.x = c4.x + fmaxf(0.f, sc * t4.x + sh);
    r.y = c4.y + fmaxf(0.f, sc * t4.y + sh);
    r.z = c4.z + fmaxf(0.f, sc * t4.z + sh);
    r.w = c4.w + fmaxf(0.f, sc * t4.w + sh);
    ((float4*)out)[idx] = r;
}

extern "C" void kernel_launch(void* const* d_in, const int* in_sizes, int n_in,
                              void* d_out, int out_size, void* d_ws, size_t ws_size,
                              hipStream_t stream) {
    const float* x     = (const float*)d_in[0];
    const float* w_qk  = (const float*)d_in[1];
    const float* w_v   = (const float*)d_in[2];
    const float* b_v   = (const float*)d_in[3];
    const float* w_x   = (const float*)d_in[4];
    const float* w_t   = (const float*)d_in[5];
    const float* b_t   = (const float*)d_in[6];
    const float* gamma = (const float*)d_in[7];
    const float* beta  = (const float*)d_in[8];
    float* out = (float*)d_out;

    char* ws = (char*)d_ws;
    unsigned short* qk_t  = (unsigned short*)ws;                      // 4 MB
    unsigned short* xv_bf = (unsigned short*)(ws + (4  << 20));       // 4 MB
    float* xc      = (float*)(ws + (8  << 20));                       // 8 MB
    unsigned short* yb0 = (unsigned short*)(ws + (16 << 20));         // 4 MB (bf16 partial Y)
    unsigned short* yb1 = (unsigned short*)(ws + (20 << 20));         // 4 MB (bf16 partial Y)
    float* t_buf   = (float*)(ws + (24 << 20));                       // 8 MB
    // part_rs (k2_sym -> k2w): 32x8x4096 f32 = 4 MB, lives in yb0's region
    // (yb0 is dead until k3, which runs after k2w consumed part_rs).
    float* part_rs = (float*)(ws + (16 << 20));
    float* cspart  = (float*)(ws + (32 << 20));                       // 256 KB (k3 -> k4)
    float* part_bn = (float*)(ws + (33 << 20));                       // 256 KB
    float* bn      = (float*)(ws + (33 << 20) + (256 << 10));         // 512 B
    // d_out doubles as scratch until k6 (k6 is the only writer of out):
    unsigned short* wstack = (unsigned short*)d_out;                  // 48 KB (k0 -> k1)
    float* lw = (float*)((char*)d_out + (256 << 10));                 // 128 KB (k2w -> k3)

    hipLaunchKernelGGL(k0_wcvt,     dim3(24),     256, 0, stream, w_qk, w_v, w_x, wstack);
    hipLaunchKernelGGL(k1_proj,     dim3(64, 8),  256, 0, stream,
                       x, wstack, b_v, qk_t, xv_bf, xc);
    hipLaunchKernelGGL(k2_sym,      dim3(4224),   256, 0, stream, qk_t, part_rs);
    hipLaunchKernelGGL(k2w,         dim3(512),    64,  0, stream, part_rs, lw);
    hipLaunchKernelGGL(k3_pv,       dim3(512),    512, 0, stream,
                       qk_t, xv_bf, lw, yb0, yb1, cspart);
    hipLaunchKernelGGL(k4_t,        dim3(64, 8),  256, 0, stream,
                       xc, yb0, yb1, cspart, w_t, b_t, t_buf, part_bn);
    hipLaunchKernelGGL(k5r,         dim3(128),    256, 0, stream, part_bn, bn);
    hipLaunchKernelGGL(k6_out,      dim3(2048),   256, 0, stream, xc, t_buf, bn, gamma, beta, out);
}

// Round 12
// 163.570 us; speedup vs baseline: 1.0409x; 1.0255x over previous
//
#include <hip/hip_runtime.h>

#define B_   8
#define C_   128
#define N_   4096
#define C2_  64

typedef __bf16 bf16x8 __attribute__((ext_vector_type(8)));
typedef float  f32x4  __attribute__((ext_vector_type(4)));

#define MFMA16(a, b, c) __builtin_amdgcn_mfma_f32_16x16x32_bf16((a), (b), (c), 0, 0, 0)

// sqrt(log2(e)): folded into w_qk by k0 so softmax uses exp2 directly
#define QK_SCALE 1.2011224087864498f

static __device__ __forceinline__ unsigned short f2bf(float f) {
    union { __bf16 b; unsigned short u; } cv;
    cv.b = (__bf16)f;
    return cv.u;
}
static __device__ __forceinline__ float bf2f(unsigned short u) {
    union { unsigned int u; float f; } cv;
    cv.u = ((unsigned int)u) << 16;
    return cv.f;
}

struct us4 { unsigned short a, b, c, d; };

// async global->LDS, 16 B per lane.  LDS dest must be linear in lane order.
static __device__ __forceinline__ void gl_lds16(const unsigned short* g, void* l) {
    __builtin_amdgcn_global_load_lds(
        (const __attribute__((address_space(1))) unsigned int*)g,
        (__attribute__((address_space(3))) unsigned int*)l,
        16, 0, 0);
}

// ---------------------------------------------------------------------------
// K0: one-time weight convert f32 -> bf16, stacked [w_qk; w_v; w_x] = [192][128].
//     QK_SCALE folded into w_qk rows.  24576 elems, grid 24 x 256 x 4.
// ---------------------------------------------------------------------------
__global__ __launch_bounds__(256) void k0_wcvt(
    const float* __restrict__ wq, const float* __restrict__ wv,
    const float* __restrict__ wx, unsigned short* __restrict__ wst)
{
    const int i4 = (blockIdx.x * 256 + threadIdx.x) * 4;   // [0, 24576)
    const int mat = i4 >> 13;                              // 8192 elems / matrix
    const float* src = (mat == 0) ? wq : (mat == 1) ? wv : wx;
    const float sc = (mat == 0) ? QK_SCALE : 1.0f;
    const float4 v = *(const float4*)(src + (i4 & 8191));
    us4 pk;
    pk.a = f2bf(v.x * sc); pk.b = f2bf(v.y * sc);
    pk.c = f2bf(v.z * sc); pk.d = f2bf(v.w * sc);
    *(us4*)(wst + i4) = pk;
}

// ---------------------------------------------------------------------------
// K1: fused projection GEMM.  D[192 o][64 n] = Wst[o][c] * x[c][n] per
//     (b, 64-n tile).  Weights (bf16 from k0) DMA-staged XOR-swizzled ->
//     LDS [192][128]; x tile transposed -> LDS bf16 x_t[64 n][136 c].
//     Epilogue: ot 0-3 -> qk_t; ot 4-7 -> xv_bf (+b_v); ot 8-11 -> xc (BF16).
// ---------------------------------------------------------------------------
__global__ __launch_bounds__(256) void k1_proj(
    const float* __restrict__ x, const unsigned short* __restrict__ wst,
    const float* __restrict__ b_v,
    unsigned short* __restrict__ qk_t, unsigned short* __restrict__ xv_bf,
    unsigned short* __restrict__ xc_bf)
{
    __shared__ __align__(16) unsigned short w_lds[192 * 128];
    __shared__ __align__(16) unsigned short x_t[64 * 136];
    const int tid = threadIdx.x;
    const int wave = tid >> 6, lane = tid & 63;
    const int quad = lane >> 4, col = lane & 15;
    const int b = blockIdx.y;
    const int n0 = blockIdx.x * 64;

    #pragma unroll
    for (int it = 0; it < 12; ++it) {
        const int idx = it * 256 + tid;                // [0, 3072)
        const int row = idx >> 4, seg = idx & 15;
        gl_lds16(wst + (size_t)row * 128 + (size_t)(seg ^ (row & 7)) * 8,
                 w_lds + idx * 8);
    }
    const float* xb = x + (size_t)b * C_ * N_ + n0;
    #pragma unroll
    for (int it = 0; it < 8; ++it) {
        const int idx = it * 256 + tid;                // [0, 2048)
        const int c = idx >> 4, n = (idx & 15) * 4;
        const float4 v = *(const float4*)(xb + (size_t)c * N_ + n);
        x_t[(n + 0) * 136 + c] = f2bf(v.x);
        x_t[(n + 1) * 136 + c] = f2bf(v.y);
        x_t[(n + 2) * 136 + c] = f2bf(v.z);
        x_t[(n + 3) * 136 + c] = f2bf(v.w);
    }
    __syncthreads();

    const int nw = wave * 16;
    bf16x8 bfr[4];
    #pragma unroll
    for (int kt = 0; kt < 4; ++kt)
        bfr[kt] = *(const bf16x8*)&x_t[(nw + col) * 136 + kt * 32 + quad * 8];

    const int n_g = n0 + nw + col;

    #pragma unroll
    for (int ot = 0; ot < 12; ++ot) {
        f32x4 acc = {0.f, 0.f, 0.f, 0.f};
        #pragma unroll
        for (int kt = 0; kt < 4; ++kt) {
            const bf16x8 afr = *(const bf16x8*)&w_lds[
                ((ot * 16 + col) << 7) + (((kt * 4 + quad) ^ (col & 7)) << 3)];
            acc = MFMA16(afr, bfr[kt], acc);
        }
        if (ot < 4) {
            us4 pk;
            pk.a = f2bf(acc[0]); pk.b = f2bf(acc[1]);
            pk.c = f2bf(acc[2]); pk.d = f2bf(acc[3]);
            *(us4*)&qk_t[(size_t)(b * N_ + n_g) * C2_ + ot * 16 + quad * 4] = pk;
        } else if (ot < 8) {
            const float4 bv4 = *(const float4*)(b_v + (ot - 4) * 16 + quad * 4);
            const float* bvp = (const float*)&bv4;
            #pragma unroll
            for (int r = 0; r < 4; ++r)
                xv_bf[(size_t)(b * C2_ + (ot - 4) * 16 + quad * 4 + r) * N_ + n_g]
                    = f2bf(acc[r] + bvp[r]);
        } else {
            #pragma unroll
            for (int r = 0; r < 4; ++r)
                xc_bf[(size_t)(b * C2_ + (ot - 8) * 16 + quad * 4 + r) * N_ + n_g]
                    = f2bf(acc[r]);
        }
    }
}

// ---------------------------------------------------------------------------
// K2_sym: partial row softmax sums exploiting E symmetry (E[n][m]=E[m][n]
//     since q,k share w_qk).  Only tiles ti<=tj computed: 528/1024 = 51.6%
//     of E-GEMM+exp2.  Off-diag tile (ti,tj): row sums -> range ti slot tj,
//     col sums -> range tj slot ti; diag: rows only.  Every (slot,range)
//     written once -> no atomics.  part_rs[32][8][4096].  Grid 4224.
// ---------------------------------------------------------------------------
__global__ __launch_bounds__(256) void k2_sym(
    const unsigned short* __restrict__ qk_t, float* __restrict__ part_rs)
{
    __shared__ __align__(16) unsigned short slab[128 * 64];
    __shared__ float cwl[4 * 128];
    const int tid = threadIdx.x;
    const int wave = tid >> 6, lane = tid & 63;
    const int quad = lane >> 4, col = lane & 15;
    const int b = blockIdx.x & 7;
    int job = blockIdx.x >> 3, ti = 0;                 // job in [0,528)
    while (job >= 32 - ti) { job -= 32 - ti; ++ti; }
    const int tj = ti + job;
    const unsigned short* qb = qk_t + (size_t)b * N_ * C2_;

    const int n_base = ti * 128 + wave * 32;
    bf16x8 a0[2], a1[2];
    #pragma unroll
    for (int s = 0; s < 2; ++s) {
        const unsigned short* p = qb + (size_t)(n_base + s * 16 + col) * C2_ + quad * 8;
        a0[s] = *(const bf16x8*)p;
        a1[s] = *(const bf16x8*)(p + 32);
    }

    #pragma unroll
    for (int r = 0; r < 4; ++r) {
        const int idx = r * 256 + tid;                 // [0, 1024)
        const int row = idx >> 3, seg = idx & 7;
        gl_lds16(qb + (size_t)(tj * 128 + row) * C2_ + (size_t)(seg ^ (row & 7)) * 8,
                 slab + idx * 8);
    }
    __syncthreads();

    float run_s[2][4];
    #pragma unroll
    for (int s = 0; s < 2; ++s)
        #pragma unroll
        for (int r = 0; r < 4; ++r) run_s[s][r] = 0.f;

    #pragma unroll
    for (int g = 0; g < 8; ++g) {
        const int row = g * 16 + col;
        const bf16x8 b0 = *(const bf16x8*)(slab + row * 64 + ((quad ^ (col & 7)) * 8));
        const bf16x8 b1 = *(const bf16x8*)(slab + row * 64 + (((4 + quad) ^ (col & 7)) * 8));
        float cs = 0.f;
        #pragma unroll
        for (int s = 0; s < 2; ++s) {
            f32x4 acc = {0.f, 0.f, 0.f, 0.f};
            __builtin_amdgcn_s_setprio(1);
            acc = MFMA16(a0[s], b0, acc);
            acc = MFMA16(a1[s], b1, acc);
            __builtin_amdgcn_s_setprio(0);
            #pragma unroll
            for (int r = 0; r < 4; ++r) {
                const float u = __builtin_amdgcn_exp2f(acc[r]);
                run_s[s][r] += u;
                cs += u;
            }
        }
        cs += __shfl_xor(cs, 16, 64);
        cs += __shfl_xor(cs, 32, 64);
        if (quad == 0) cwl[wave * 128 + g * 16 + col] = cs;
    }
    __syncthreads();
    if (ti != tj && tid < 128) {
        const float c = cwl[tid] + cwl[128 + tid] + cwl[256 + tid] + cwl[384 + tid];
        part_rs[((size_t)(ti * 8 + b) << 12) + tj * 128 + tid] = c;
    }

    #pragma unroll
    for (int s = 0; s < 2; ++s)
        #pragma unroll
        for (int r = 0; r < 4; ++r) {
            #pragma unroll
            for (int off = 1; off < 16; off <<= 1)
                run_s[s][r] += __shfl_xor(run_s[s][r], off, 64);
        }
    if (col == 0) {
        #pragma unroll
        for (int s = 0; s < 2; ++s)
            #pragma unroll
            for (int r = 0; r < 4; ++r)
                part_rs[((size_t)(tj * 8 + b) << 12) + n_base + s * 16 + quad * 4 + r]
                    = run_s[s][r];
    }
}

// ---------------------------------------------------------------------------
// K2w: lw[b][n] = -log2( sum_{t<32} part_rs[t][b][n] ).  Grid 512 x 64.
// ---------------------------------------------------------------------------
__global__ __launch_bounds__(64) void k2w(
    const float* __restrict__ part_rs, float* __restrict__ lw)
{
    const int b = blockIdx.x & 7;
    const int n = (blockIdx.x >> 3) * 64 + threadIdx.x;
    float s = 0.f;
    #pragma unroll
    for (int t = 0; t < 32; ++t)
        s += part_rs[((size_t)(t * 8 + b) << 12) + n];
    lw[b * N_ + n] = -__log2f(s);
}

// ---------------------------------------------------------------------------
// K3: R7 structure + lw via MFMA C-operand, with the lw4 loads PREFETCHED
//     one chunk ahead in registers (R11 lesson: loading them at use sits in
//     the E serial chain and cost 3us).  S'' = exp2(E+lw); PV uses raw xv;
//     colsum A = ones.  DMA dbuf staging, 1 barrier/chunk, wave-private stS.
//     8 waves, 32-m/wave, split-K=2, grid 512 = 2 blk/CU, 16 waves/CU.
//     launch_bounds(512,4): cap 128 >> natural ~110 -> no spill.
// ---------------------------------------------------------------------------
__global__ __launch_bounds__(512, 4) void k3_pv(
    const unsigned short* __restrict__ qk_t, const unsigned short* __restrict__ xv_bf,
    const float* __restrict__ lw,
    unsigned short* __restrict__ yb0, unsigned short* __restrict__ yb1,
    float* __restrict__ cspart)
{
    // 0..16K: qk dbuf | 16K..32K: xv dbuf | 32K..52K: stS (8 waves x 2560 B)
    __shared__ __align__(16) unsigned char lds_raw[32768 + 8 * 2560];
    const int tid = threadIdx.x;
    const int wave = tid >> 6, lane = tid & 63;
    const int quad = lane >> 4, col = lane & 15;
    const int nh2 = wave & 1, mh = wave >> 1;        // mh 0..3
    const int b = blockIdx.x & 7;
    const int m_blk = ((blockIdx.x >> 3) & 31) * 128;
    const int sk = blockIdx.x >> 8;                  // 0..1 (split-K index)
    const int n_start = sk * 2048;
    const int n_chunks = 32;
    const int m_wave = m_blk + mh * 32;
    const unsigned short* qb = qk_t + (size_t)b * N_ * C2_;
    const unsigned short* vb = xv_bf + (size_t)b * C2_ * N_;
    const float* ln = lw + b * N_;
    unsigned short* yp = (sk == 0) ? yb0 : yb1;

    // persistent B-operands for E: this wave's 32 m-cols (2 groups of 16)
    bf16x8 kb0[2], kb1[2];
    #pragma unroll
    for (int g = 0; g < 2; ++g) {
        const unsigned short* p = qb + (size_t)(m_wave + g * 16 + col) * C2_ + quad * 8;
        kb0[g] = *(const bf16x8*)p;
        kb1[g] = *(const bf16x8*)(p + 32);
    }

    // colsum A-operand: constant ones (S'' already carries the row scale)
    bf16x8 ones;
    #pragma unroll
    for (int j = 0; j < 8; ++j) ones[j] = (__bf16)1.0f;

    unsigned short* stS = (unsigned short*)(lds_raw + 32768 + wave * 2560); // [g][col][40]

    // stage one 64n qk slab + 64ch xv tile (8 KB each): 1 DMA/lane/array
    auto stage = [&](int n0, int p) {
        unsigned char* qbase = lds_raw + p * 8192;
        unsigned char* vbase = lds_raw + 16384 + p * 8192;
        const int row = tid >> 3, seg = tid & 7;
        const int ss = seg ^ (row & 7);
        gl_lds16(qb + (size_t)(n0 + row) * C2_ + (size_t)ss * 8, qbase + tid * 16);
        gl_lds16(vb + (size_t)row * N_ + n0 + ss * 8, vbase + tid * 16);
    };

    f32x4 accY[2][4];   // [g][os]
    #pragma unroll
    for (int g = 0; g < 2; ++g)
        #pragma unroll
        for (int os = 0; os < 4; ++os) accY[g][os] = (f32x4){0.f, 0.f, 0.f, 0.f};
    f32x4 csacc[2];
    #pragma unroll
    for (int g = 0; g < 2; ++g) csacc[g] = (f32x4){0.f, 0.f, 0.f, 0.f};

    // lw prefetch: this wave's 8 lw values per chunk (ns=0/1), one chunk ahead
    const float* lwp = ln + n_start + nh2 * 32 + quad * 4;
    float4 lwA = *(const float4*)(lwp);         // chunk 0, ns=0
    float4 lwB = *(const float4*)(lwp + 16);    // chunk 0, ns=1

    stage(n_start, 0);
    __syncthreads();

    for (int c = 0; c < n_chunks; ++c) {
        const int n0 = n_start + c * 64;
        const int p = c & 1;
        if (c + 1 < n_chunks) stage(n0 + 64, 1 - p);

        const unsigned short* qt = (const unsigned short*)(lds_raw + p * 8192);
        const unsigned short* vt = (const unsigned short*)(lds_raw + 16384 + p * 8192);

        // E phase; S'' = exp2(E + lw[n]) -> LDS (lw enters as MFMA C-init,
        // prefetched last chunk -> off the serial chain)
        #pragma unroll
        for (int ns = 0; ns < 2; ++ns) {
            const int row = nh2 * 32 + ns * 16 + col;
            const bf16x8 qa0 = *(const bf16x8*)(qt + row * 64 + ((quad ^ (col & 7)) * 8));
            const bf16x8 qa1 = *(const bf16x8*)(qt + row * 64 + (((4 + quad) ^ (col & 7)) * 8));
            const float4 lw4 = ns ? lwB : lwA;
            #pragma unroll
            for (int g = 0; g < 2; ++g) {
                f32x4 acc = {lw4.x, lw4.y, lw4.z, lw4.w};
                acc = MFMA16(qa0, kb0[g], acc);
                acc = MFMA16(qa1, kb1[g], acc);
                union { unsigned short us[4]; uint2 u2; } pk;
                #pragma unroll
                for (int r = 0; r < 4; ++r)
                    pk.us[r] = f2bf(__builtin_amdgcn_exp2f(acc[r]));
                *(uint2*)&stS[(g * 16 + col) * 40 + ns * 16 + quad * 4] = pk.u2;
            }
        }

        // prefetch lw for next chunk (covered by PV below)
        if (c + 1 < n_chunks) {
            lwA = *(const float4*)(lwp + (c + 1) * 64);
            lwB = *(const float4*)(lwp + (c + 1) * 64 + 16);
        }

        // same-wave round-trip: S'' as B-operand (K = this wave's 32 n)
        bf16x8 sB[2];
        #pragma unroll
        for (int g = 0; g < 2; ++g)
            sB[g] = *(const bf16x8*)&stS[(g * 16 + col) * 40 + quad * 8];

        // colsum via MFMA with A = ones -> D rows all = colsum of S''
        #pragma unroll
        for (int g = 0; g < 2; ++g)
            csacc[g] = MFMA16(ones, sB[g], csacc[g]);

        // PV: A = raw xv rows (o), k = this wave's 32 n
        #pragma unroll
        for (int os = 0; os < 4; ++os) {
            const bf16x8 va = *(const bf16x8*)(vt + (os * 16 + col) * 64 +
                                               (((nh2 * 4 + quad) ^ (col & 7)) * 8));
            #pragma unroll
            for (int g = 0; g < 2; ++g)
                accY[g][os] = MFMA16(va, sB[g], accY[g][os]);
        }
        __syncthreads();
    }

    // epilogue: combine the two n-halves (waves nh2=1 -> LDS; nh2=0 adds+writes)
    float* cmb = (float*)lds_raw;              // 32 KB: [mh][g*4+os][r][lane]
    float* csc = (float*)(lds_raw + 32768);    // 2 KB:  [mh][g][lane]
    if (nh2 == 1) {
        #pragma unroll
        for (int g = 0; g < 2; ++g) {
            #pragma unroll
            for (int os = 0; os < 4; ++os)
                #pragma unroll
                for (int r = 0; r < 4; ++r)
                    cmb[((mh * 8 + g * 4 + os) * 4 + r) * 64 + lane] = accY[g][os][r];
            csc[(mh * 2 + g) * 64 + lane] = csacc[g][0];
        }
    }
    __syncthreads();
    if (nh2 == 0) {
        #pragma unroll
        for (int g = 0; g < 2; ++g) {
            const float cs = csacc[g][0] + csc[(mh * 2 + g) * 64 + lane];
            if (lane < 16)
                cspart[((size_t)sk * 8 + b) * N_ + m_wave + g * 16 + lane] = cs;
            #pragma unroll
            for (int os = 0; os < 4; ++os)
                #pragma unroll
                for (int r = 0; r < 4; ++r) {
                    const float v = accY[g][os][r] +
                        cmb[((mh * 8 + g * 4 + os) * 4 + r) * 64 + lane];
                    yp[(size_t)(b * C2_ + os * 16 + quad * 4 + r) * N_ + m_wave + g * 16 + col]
                        = f2bf(v);
                }
        }
    }
}

// ---------------------------------------------------------------------------
// K4: fused partial-combine + w_t GEMM (MFMA) + BN partial stats.
//     Grid (64, 8).  cinv = 1/(eps+sum cspart); d = xc - (y0+y1)*cinv
//     (xc now BF16) staged TRANSPOSED to LDS bf16 d_t[n][72]; w_t [o][72].
//     Wave = o-tile; K=64.  t -> t_bf (BF16; stats from unrounded f32);
//     per-block channel partials -> part_bn[c][blk].
// ---------------------------------------------------------------------------
__global__ __launch_bounds__(256) void k4_t(
    const unsigned short* __restrict__ xc_bf, const unsigned short* __restrict__ y0,
    const unsigned short* __restrict__ y1,
    const float* __restrict__ cspart, const float* __restrict__ w_t,
    const float* __restrict__ b_t, unsigned short* __restrict__ t_bf,
    float* __restrict__ part_bn)
{
    __shared__ __align__(16) unsigned short wlds[64 * 72];
    __shared__ __align__(16) unsigned short d_t[64 * 72];
    __shared__ float cinv[64];
    const int tid = threadIdx.x;
    const int wave = tid >> 6, lane = tid & 63;
    const int quad = lane >> 4, col = lane & 15;
    const int b = blockIdx.y;
    const int n0 = blockIdx.x * 64;
    const size_t base = (size_t)b * C2_ * N_;

    #pragma unroll
    for (int it = 0; it < 4; ++it) {
        const int idx4 = it * 256 + tid;               // [0, 1024)
        const int o = idx4 >> 4, i4 = (idx4 & 15) * 4;
        const float4 v = *(const float4*)(w_t + o * 64 + i4);
        us4 pk;
        pk.a = f2bf(v.x); pk.b = f2bf(v.y); pk.c = f2bf(v.z); pk.d = f2bf(v.w);
        *(us4*)&wlds[o * 72 + i4] = pk;
    }
    if (tid < 64) {
        const int n = n0 + tid;
        const float cs = cspart[(size_t)b * N_ + n] + cspart[(size_t)(8 + b) * N_ + n];
        cinv[tid] = 1.0f / (1e-9f + cs);
    }
    __syncthreads();

    #pragma unroll
    for (int it = 0; it < 4; ++it) {
        const int idx4 = it * 256 + tid;               // [0, 1024)
        const int i = idx4 >> 4, n4 = (idx4 & 15) * 4;
        const size_t g = base + (size_t)i * N_ + n0 + n4;
        const us4 cx = *(const us4*)(xc_bf + g);
        const us4 u0 = *(const us4*)(y0 + g);
        const us4 u1 = *(const us4*)(y1 + g);
        d_t[(n4 + 0) * 72 + i] = f2bf(bf2f(cx.a) - (bf2f(u0.a) + bf2f(u1.a)) * cinv[n4 + 0]);
        d_t[(n4 + 1) * 72 + i] = f2bf(bf2f(cx.b) - (bf2f(u0.b) + bf2f(u1.b)) * cinv[n4 + 1]);
        d_t[(n4 + 2) * 72 + i] = f2bf(bf2f(cx.c) - (bf2f(u0.c) + bf2f(u1.c)) * cinv[n4 + 2]);
        d_t[(n4 + 3) * 72 + i] = f2bf(bf2f(cx.d) - (bf2f(u0.d) + bf2f(u1.d)) * cinv[n4 + 3]);
    }
    __syncthreads();

    const int ow = wave * 16;
    bf16x8 afr[2];
    #pragma unroll
    for (int kt = 0; kt < 2; ++kt)
        afr[kt] = *(const bf16x8*)&wlds[(ow + col) * 72 + kt * 32 + quad * 8];
    const float4 bt4 = *(const float4*)(b_t + ow + quad * 4);
    const float* btp = (const float*)&bt4;

    float s[4] = {0.f, 0.f, 0.f, 0.f}, q2[4] = {0.f, 0.f, 0.f, 0.f};
    #pragma unroll
    for (int ns = 0; ns < 4; ++ns) {
        f32x4 acc = {0.f, 0.f, 0.f, 0.f};
        #pragma unroll
        for (int kt = 0; kt < 2; ++kt) {
            const bf16x8 bfr = *(const bf16x8*)&d_t[(ns * 16 + col) * 72 + kt * 32 + quad * 8];
            acc = MFMA16(afr[kt], bfr, acc);
        }
        #pragma unroll
        for (int r = 0; r < 4; ++r) {
            const float t = acc[r] + btp[r];
            t_bf[base + (size_t)(ow + quad * 4 + r) * N_ + n0 + ns * 16 + col] = f2bf(t);
            s[r] += t;
            q2[r] += t * t;
        }
    }
    #pragma unroll
    for (int r = 0; r < 4; ++r) {
        #pragma unroll
        for (int off = 1; off < 16; off <<= 1) {
            s[r]  += __shfl_xor(s[r],  off, 64);
            q2[r] += __shfl_xor(q2[r], off, 64);
        }
    }
    if (col == 0) {
        const int blk = blockIdx.x * 8 + b;            // [0, 512)
        #pragma unroll
        for (int r = 0; r < 4; ++r) {
            part_bn[(size_t)(ow + quad * 4 + r) * 512 + blk]      = s[r];
            part_bn[(size_t)(64 + ow + quad * 4 + r) * 512 + blk] = q2[r];
        }
    }
}

// K5r: bn[c] = sum_blk part_bn[c][blk], c in [0,128)
__global__ __launch_bounds__(256) void k5r(
    const float* __restrict__ part_bn, float* __restrict__ bn)
{
    const int c = blockIdx.x;
    const int tid = threadIdx.x, wave = tid >> 6, lane = tid & 63;
    float s = 0.f;
    for (int j = tid; j < 512; j += 256) s += part_bn[(size_t)c * 512 + j];
    #pragma unroll
    for (int off = 1; off < 64; off <<= 1) s += __shfl_xor(s, off, 64);
    __shared__ float red[4];
    if (lane == 0) red[wave] = s;
    __syncthreads();
    if (tid == 0) bn[c] = red[0] + red[1] + red[2] + red[3];
}

// ---------------------------------------------------------------------------
// K6: out = xc + relu(gamma * (t - mean) * rsqrt(var + eps) + beta)
//     xc, t read as BF16 (us4); out written f32.
// ---------------------------------------------------------------------------
__global__ __launch_bounds__(256) void k6_out(
    const unsigned short* __restrict__ xc_bf, const unsigned short* __restrict__ t_bf,
    const float* __restrict__ bn, const float* __restrict__ gamma,
    const float* __restrict__ beta, float* __restrict__ out)
{
    const int idx = blockIdx.x * 256 + threadIdx.x;
    const int o = (idx >> 10) & 63;
    const float invC = 1.0f / (float)(B_ * N_);
    const float mean = bn[o] * invC;
    const float var  = bn[64 + o] * invC - mean * mean;
    const float sc = gamma[o] * rsqrtf(var + 1e-5f);
    const float sh = beta[o] - mean * sc;
    const us4 t4 = ((const us4*)t_bf)[idx];
    const us4 c4 = ((const us4*)xc_bf)[idx];
    float4 r;
    r.x = bf2f(c4.a) + fmaxf(0.f, sc * bf2f(t4.a) + sh);
    r.y = bf2f(c4.b) + fmaxf(0.f, sc * bf2f(t4.b) + sh);
    r.z = bf2f(c4.c) + fmaxf(0.f, sc * bf2f(t4.c) + sh);
    r.w = bf2f(c4.d) + fmaxf(0.f, sc * bf2f(t4.d) + sh);
    ((float4*)out)[idx] = r;
}

extern "C" void kernel_launch(void* const* d_in, const int* in_sizes, int n_in,
                              void* d_out, int out_size, void* d_ws, size_t ws_size,
                              hipStream_t stream) {
    const float* x     = (const float*)d_in[0];
    const float* w_qk  = (const float*)d_in[1];
    const float* w_v   = (const float*)d_in[2];
    const float* b_v   = (const float*)d_in[3];
    const float* w_x   = (const float*)d_in[4];
    const float* w_t   = (const float*)d_in[5];
    const float* b_t   = (const float*)d_in[6];
    const float* gamma = (const float*)d_in[7];
    const float* beta  = (const float*)d_in[8];
    float* out = (float*)d_out;

    char* ws = (char*)d_ws;
    unsigned short* qk_t  = (unsigned short*)ws;                      // 4 MB
    unsigned short* xv_bf = (unsigned short*)(ws + (4  << 20));       // 4 MB
    unsigned short* xc_bf = (unsigned short*)(ws + (8  << 20));       // 4 MB (bf16)
    unsigned short* t_bf  = (unsigned short*)(ws + (12 << 20));       // 4 MB (bf16)
    unsigned short* yb0 = (unsigned short*)(ws + (16 << 20));         // 4 MB (bf16 partial Y)
    unsigned short* yb1 = (unsigned short*)(ws + (20 << 20));         // 4 MB (bf16 partial Y)
    // part_rs (k2_sym -> k2w): 32x8x4096 f32 = 4 MB, in yb0's future region?
    // NO -- yb0 is written by k3 AFTER k2w consumed part_rs; but k2_sym runs
    // before k3, and yb0 region [16,20) MB is free until k3.  part_rs lives
    // at [24,28) MB instead to keep regions disjoint and obvious.
    float* part_rs = (float*)(ws + (24 << 20));                       // 4 MB
    float* cspart  = (float*)(ws + (32 << 20));                       // 256 KB (k3 -> k4)
    float* part_bn = (float*)(ws + (33 << 20));                       // 256 KB
    float* bn      = (float*)(ws + (33 << 20) + (256 << 10));         // 512 B
    // d_out doubles as scratch until k6 (k6 is the only writer of out):
    unsigned short* wstack = (unsigned short*)d_out;                  // 48 KB (k0 -> k1)
    float* lw = (float*)((char*)d_out + (256 << 10));                 // 128 KB (k2w -> k3)

    hipLaunchKernelGGL(k0_wcvt,     dim3(24),     256, 0, stream, w_qk, w_v, w_x, wstack);
    hipLaunchKernelGGL(k1_proj,     dim3(64, 8),  256, 0, stream,
                       x, wstack, b_v, qk_t, xv_bf, xc_bf);
    hipLaunchKernelGGL(k2_sym,      dim3(4224),   256, 0, stream, qk_t, part_rs);
    hipLaunchKernelGGL(k2w,         dim3(512),    64,  0, stream, part_rs, lw);
    hipLaunchKernelGGL(k3_pv,       dim3(512),    512, 0, stream,
                       qk_t, xv_bf, lw, yb0, yb1, cspart);
    hipLaunchKernelGGL(k4_t,        dim3(64, 8),  256, 0, stream,
                       xc_bf, yb0, yb1, cspart, w_t, b_t, t_bf, part_bn);
    hipLaunchKernelGGL(k5r,         dim3(128),    256, 0, stream, part_bn, bn);
    hipLaunchKernelGGL(k6_out,      dim3(2048),   256, 0, stream, xc_bf, t_bf, bn, gamma, beta, out);
}